// Round 2
// baseline (3207.172 us; speedup 1.0000x reference)
//
#include <hip/hip_runtime.h>
#include <hip/hip_cooperative_groups.h>
#include <stdint.h>
#include <math.h>

namespace cg = cooperative_groups;

// ---------------------------------------------------------------------------
// RSNN forward, MI355X. EXACT integer hidden GEMM (absmax 0.0156): 27-bit
// fixed-point weights -> 3 signed base-256 i8 digit planes, binary
// activations, i32 MFMA, exact int64 recombination, single fp32 round,
// fp32 program-order decay.
// Round-12: ONE persistent cooperative kernel (256 blocks x 512 threads,
// 1 block/CU, grid.sync() per step). Weights resident in 144 VGPRs/thread
// (breg[6][2][3]) -- loaded ONCE, removes 295 KB/CU/step of L2 streaming.
// Hidden membrane Hm lives in 4 registers/thread (same 4 cells every step);
// o-state (Om/Osp/Osu/Mo) lives in wave-7 registers. WhoL LDS loaded once.
// K-loop per slab: 4 A-loads + 24 MFMAs. final_k folded into iteration 50.
// Removes 50 launch gaps + all Hm/o-state global round-trips.
// ---------------------------------------------------------------------------

#define B_   256
#define T_   50
#define I_   1024
#define H_   2048
#define O_   20
#define XIN_T  262144    // input bytes per t: 4 bg * 16 kx * 4096
#define XS_BUF 524288    // one spike buffer: 4 bg * 32 kx * 4096
#define WNT 294912       // weight bytes per nt (32 cols): 3 * 48 * 2048
#define WPL 98304        // bytes per plane within an nt

typedef __attribute__((ext_vector_type(4))) int intx4;
typedef long long ll_t;

// ---------------------------------------------------------------------------
// Weight prep: digit p of W(n,kk) -> [nt 64][p 3][kx 48][row 32][64B]
// ---------------------------------------------------------------------------
__device__ __forceinline__ int digit_of(float v, int p) {
  int W = (int)rintf(v * 134217728.0f);   // exact: |W| <= 2^22
  int c0 = ((W + 128) & 255) - 128;
  int W1 = (W - c0) >> 8;
  int c1 = ((W1 + 128) & 255) - 128;
  int W2 = (W1 - c1) >> 8;
  return (p == 0) ? c0 : (p == 1) ? c1 : W2;
}

__global__ void prep_w(const float* __restrict__ w_ih,
                       const float* __restrict__ w_hh,
                       int8_t* __restrict__ Wtl) {
  int blk = blockIdx.x;
  int n = blk / 9, kg = blk % 9;
  int k9 = (kg * 256 + (int)threadIdx.x) * 4;   // [0, 9216)
  int p = k9 / 3072, kk = k9 % 3072;
  const float* src = (kk < 1024) ? (w_ih + n * I_ + kk)
                                 : (w_hh + n * H_ + (kk - 1024));
  float4 v = *(const float4*)src;
  int d0 = digit_of(v.x, p) & 255;
  int d1 = digit_of(v.y, p) & 255;
  int d2 = digit_of(v.z, p) & 255;
  int d3 = digit_of(v.w, p) & 255;
  int packed = d0 | (d1 << 8) | (d2 << 16) | (d3 << 24);
  size_t off = (size_t)(n >> 5) * WNT + (size_t)p * WPL + (kk >> 6) * 2048 +
               (n & 31) * 64 + (kk & 63);
  *(int*)(Wtl + off) = packed;
}

// ---------------------------------------------------------------------------
// Init: pack input for ALL t, zero spike buf0, tables.
// ---------------------------------------------------------------------------
__global__ void init_k(int8_t* __restrict__ Xin, int8_t* __restrict__ Xs,
                       const float* __restrict__ input,
                       const float* __restrict__ tau_h,
                       const float* __restrict__ tau_o,
                       float* __restrict__ AlphaH, float* __restrict__ AlphaO,
                       const float* __restrict__ w_ho,
                       double* __restrict__ WhoD) {
  int id = blockIdx.x * 256 + threadIdx.x;   // [0, 65536)
  {
    int b = id >> 8, i4 = (id & 255) * 4;
    for (int t = 0; t < T_; ++t) {
      float4 v = *(const float4*)(input + ((size_t)(b * T_ + t) << 10) + i4);
      uchar4 pk;
      pk.x = v.x > 0.5f ? 1 : 0;
      pk.y = v.y > 0.5f ? 1 : 0;
      pk.z = v.z > 0.5f ? 1 : 0;
      pk.w = v.w > 0.5f ? 1 : 0;
      *(uchar4*)(Xin + (size_t)t * XIN_T + (b >> 6) * 65536 + (i4 >> 6) * 4096 +
                 (b & 63) * 64 + (i4 & 63)) = pk;
    }
  }
  *(double*)(Xs + (size_t)id * 8) = 0.0;        // zero spike buf0
  if (id < 64 * O_ * 32) {                      // WhoD [nt 64][o 20][hl 32]
    int nt = id / 640, rem = id % 640, o = rem / 32, hl = rem & 31;
    WhoD[id] = (double)w_ho[o * H_ + nt * 32 + hl];
  }
  if (id < H_) AlphaH[id] = (float)exp((double)(-1.0f / tau_h[id]));
  if (id < O_) AlphaO[id] = (float)exp((double)(-1.0f / tau_o[id]));
}

// ---------------------------------------------------------------------------
// Persistent kernel: 256 blocks x 512 threads (1/CU, 2 waves/SIMD, 256-reg).
// Block (nt in [0,64), mg in [0,4)): 64 batch x 32 h, full K, all 50 steps.
// Wave k in [0,8) = K-eighth (6 slabs), 4fr x 2fc x 3p acc per wave.
// ---------------------------------------------------------------------------
__global__ __launch_bounds__(512, 2) void rsnn_k(
    const int8_t* __restrict__ Wtl, const int8_t* __restrict__ Xin,
    int8_t* __restrict__ Xs, double* __restrict__ Po,
    const double* __restrict__ WhoD, const float* __restrict__ AlphaH,
    const float* __restrict__ AlphaO, float* __restrict__ out) {
  cg::grid_group grid = cg::this_grid();
  __shared__ double WhoL[640];
  __shared__ __align__(16) int8_t red[98304];   // [wave 8][frag 12][lane 64][16B]
  __shared__ int8_t spk_lT[2048];               // [h 32][b 64]

  const int j = blockIdx.x;                     // [0,256)
  const int nt = (j & 7) * 8 + ((j >> 3) & 7);  // same nt -> same j%8 (XCD)
  const int mg = j >> 6;                        // 64-batch group [0,4)
  const int tid = threadIdx.x;
  const int l = tid & 63, k = tid >> 6;
  const int r_ = l & 15, q = l >> 4;

  for (int i = tid; i < 640; i += 512) WhoL[i] = WhoD[nt * 640 + i];

  // fixed per-thread epilogue coordinates (wave role is static)
  const int fr_e = (k < 4) ? (k >> 1) : (2 + ((k - 4) >> 1));
  const int fc_e = k & 1;
  const int h_e = nt * 32 + fc_e * 16 + r_;
  const float alpha_e = AlphaH[h_e];
  const float alphaO_r = (l < O_) ? AlphaO[l] : 0.f;

  // persistent per-thread state
  float hm[4] = {0.f, 0.f, 0.f, 0.f};          // membrane, 4 batch rows
  float om = 0.f, osp = 0.f, osu = 0.f, mo = 0.f;  // wave-7 lanes l<20

  // resident weights: K-eighth of the 32-h panel, [slab 6][fc 2][p 3]
  const int u0 = k * 6;
  const int8_t* Bw = Wtl + (size_t)nt * WNT + r_ * 64 + q * 16;
  intx4 breg[6][2][3];
#pragma unroll
  for (int i = 0; i < 6; ++i)
#pragma unroll
    for (int p = 0; p < 3; ++p)
#pragma unroll
      for (int fc = 0; fc < 2; ++fc)
        breg[i][fc][p] =
            *(const intx4*)(Bw + (size_t)(u0 + i) * 2048 + p * WPL + fc * 1024);

  const int arow = r_ * 64 + q * 16;

#define REDP(w, idx) (red + (((w) * 12 + (idx)) * 64 + l) * 16)

  for (int t = 0; t <= T_; ++t) {
    grid.sync();   // spikes(t), Po(t-1) visible across XCDs

    if (t < T_) {
      const int8_t* Ain = Xin + (size_t)t * XIN_T + mg * 65536 + arow;
      const int8_t* Asp = Xs + (size_t)(t & 1) * XS_BUF + mg * 131072 + arow;
      int8_t* Xw = Xs + (size_t)((t + 1) & 1) * XS_BUF;

      intx4 acc[4][2][3];
#pragma unroll
      for (int fr = 0; fr < 4; ++fr)
#pragma unroll
        for (int fc = 0; fc < 2; ++fc)
#pragma unroll
          for (int p = 0; p < 3; ++p) acc[fr][fc][p] = (intx4){0, 0, 0, 0};

      // ---- K-loop: 6 slabs, A loads only (B resident) ----
#pragma unroll
      for (int i = 0; i < 6; ++i) {
        const int u = u0 + i;
        const int8_t* ap =
            (u < 16) ? (Ain + u * 4096) : (Asp + (u - 16) * 4096);
        intx4 a0 = *(const intx4*)ap;
        intx4 a1 = *(const intx4*)(ap + 1024);
        intx4 a2 = *(const intx4*)(ap + 2048);
        intx4 a3 = *(const intx4*)(ap + 3072);
#pragma unroll
        for (int p = 0; p < 3; ++p)
#pragma unroll
          for (int fc = 0; fc < 2; ++fc) {
            acc[0][fc][p] = __builtin_amdgcn_mfma_i32_16x16x64_i8(
                a0, breg[i][fc][p], acc[0][fc][p], 0, 0, 0);
            acc[1][fc][p] = __builtin_amdgcn_mfma_i32_16x16x64_i8(
                a1, breg[i][fc][p], acc[1][fc][p], 0, 0, 0);
            acc[2][fc][p] = __builtin_amdgcn_mfma_i32_16x16x64_i8(
                a2, breg[i][fc][p], acc[2][fc][p], 0, 0, 0);
            acc[3][fc][p] = __builtin_amdgcn_mfma_i32_16x16x64_i8(
                a3, breg[i][fc][p], acc[3][fc][p], 0, 0, 0);
          }
      }

      // ---- epilogue body: exact recombine, reg-resident membrane ----
      auto epilogue = [&](intx4 s0, intx4 s1, intx4 s2) {
        unsigned spkpack = 0;
#pragma unroll
        for (int jj = 0; jj < 4; ++jj) {
          ll_t Sv = (ll_t)s0[jj] + ((ll_t)s1[jj] << 8) + ((ll_t)s2[jj] << 16);
          float M = (float)((double)Sv * 7.450580596923828125e-9);  // * 2^-27
          float hp = hm[jj];
          float spf = (hp - 0.3f) > 0.f ? 1.f : 0.f;
          float hmn = M + hp * alpha_e * (1.0f - spf);   // fp32 program order
          hm[jj] = hmn;
          unsigned spk = (hmn - 0.3f) > 0.f ? 1u : 0u;
          const int brl = fr_e * 16 + q * 4 + jj;        // batch row [0,64)
          Xw[mg * 131072 + (h_e >> 6) * 4096 + brl * 64 + (h_e & 63)] =
              (int8_t)spk;
          spkpack |= spk << (8 * jj);
        }
        *(unsigned*)(spk_lT + (fc_e * 16 + r_) * 64 + fr_e * 16 + q * 4) =
            spkpack;
      };

      // ---- Round A: fragments fr 0..1 -> waves 0..3 merge + epilogue ----
#pragma unroll
      for (int fr = 0; fr < 2; ++fr)
#pragma unroll
        for (int fc = 0; fc < 2; ++fc)
#pragma unroll
          for (int p = 0; p < 3; ++p)
            *(intx4*)REDP(k, (fr * 2 + fc) * 3 + p) = acc[fr][fc][p];
      __syncthreads();
      if (k < 4) {
        const int base = (fr_e * 2 + fc_e) * 3;
        intx4 s0 = (intx4){0, 0, 0, 0}, s1 = s0, s2 = s0;
#pragma unroll
        for (int w = 0; w < 8; ++w) {
          s0 = s0 + *(const intx4*)REDP(w, base + 0);
          s1 = s1 + *(const intx4*)REDP(w, base + 1);
          s2 = s2 + *(const intx4*)REDP(w, base + 2);
        }
        epilogue(s0, s1, s2);
      }
      __syncthreads();
      // ---- Round B: fragments fr 2..3 -> waves 4..7 merge + epilogue ----
#pragma unroll
      for (int fr = 0; fr < 2; ++fr)
#pragma unroll
        for (int fc = 0; fc < 2; ++fc)
#pragma unroll
          for (int p = 0; p < 3; ++p)
            *(intx4*)REDP(k, (fr * 2 + fc) * 3 + p) = acc[2 + fr][fc][p];
      __syncthreads();
      if (k >= 4) {
        const int base = ((fr_e - 2) * 2 + fc_e) * 3;
        intx4 s0 = (intx4){0, 0, 0, 0}, s1 = s0, s2 = s0;
#pragma unroll
        for (int w = 0; w < 8; ++w) {
          s0 = s0 + *(const intx4*)REDP(w, base + 0);
          s1 = s1 + *(const intx4*)REDP(w, base + 1);
          s2 = s2 + *(const intx4*)REDP(w, base + 2);
        }
        epilogue(s0, s1, s2);
      }
      __syncthreads();

      // ---- o-partials (waves 0-3): 32-h double dot -> Po[t&1][b][nt][o] ----
      if (tid < 256) {
        const int bl = tid >> 2, og = (tid & 3) * 5;
        const double* W0 = WhoL + og * 32;
        double a0 = 0, a1 = 0, a2 = 0, a3 = 0, a4 = 0;
#pragma unroll
        for (int hl = 0; hl < 32; ++hl) {
          double m = (double)spk_lT[hl * 64 + bl];
          a0 += m * W0[hl];
          a1 += m * W0[32 + hl];
          a2 += m * W0[64 + hl];
          a3 += m * W0[96 + hl];
          a4 += m * W0[128 + hl];
        }
        double* dst =
            Po + ((size_t)((t & 1) * 256 + mg * 64 + bl) * 64 + nt) * 20 + og;
        dst[0] = a0; dst[1] = a1; dst[2] = a2; dst[3] = a3; dst[4] = a4;
      }
    }

    // ---- head: o-phase for step t-1 (wave 7, batch j); t=50 -> final+out --
    if (k == 7 && t > 0) {
      float m = -3.0e38f;
      if (l < O_) {
        const double* pp =
            Po + ((size_t)(((t - 1) & 1) * 256 + j) * 64) * 20 + l;
        double s = 0.0;
#pragma unroll
        for (int n2 = 0; n2 < 64; ++n2) s += pp[n2 * 20];
        m = om * alphaO_r * (1.0f - osp) + (float)s;
      }
      float mx = m;
#pragma unroll
      for (int off = 16; off > 0; off >>= 1)
        mx = fmaxf(mx, __shfl_xor(mx, off, 32));
      float eo = (l < O_) ? expf(m - mx) : 0.f;
      float se = eo;
#pragma unroll
      for (int off = 16; off > 0; off >>= 1) se += __shfl_xor(se, off, 32);
      if (l < O_) {
        float sp = (m - 0.3f) > 0.f ? 1.f : 0.f;
        if (t < T_) {
          om = m; osp = sp; osu += sp; mo += eo / se;
        } else {
          out[j * O_ + l] = (osu + sp) / 50.0f;
          out[B_ * O_ + j * O_ + l] = mo + eo / se;
        }
      }
    }
  }
#undef REDP
}

// ---------------------------------------------------------------------------
extern "C" void kernel_launch(void* const* d_in, const int* in_sizes, int n_in,
                              void* d_out, int out_size, void* d_ws, size_t ws_size,
                              hipStream_t stream) {
  const float* input = (const float*)d_in[0];
  const float* w_ih  = (const float*)d_in[1];
  const float* w_hh  = (const float*)d_in[2];
  const float* w_ho  = (const float*)d_in[3];
  const float* tau_h = (const float*)d_in[4];
  const float* tau_o = (const float*)d_in[5];

  char* ws = (char*)d_ws;
  // layout (bytes):
  // Wtl    @ 0          18,874,368
  // Xin    @ 18874368   13,107,200
  // Xs     @ 31981568    1,048,576
  // Po     @ 33030144    5,242,880   (2 x 256 x 64 x 20 doubles)
  // WhoD   @ 40370176      327,680
  // AlphaH @ 40697856        8,192
  // AlphaO @ 40706048          128
  int8_t* Wtl    = (int8_t*)(ws);
  int8_t* Xin    = (int8_t*)(ws + 18874368);
  int8_t* Xs     = (int8_t*)(ws + 31981568);
  double* Po     = (double*)(ws + 33030144);
  double* WhoD   = (double*)(ws + 40370176);
  float*  AlphaH = (float*)(ws + 40697856);
  float*  AlphaO = (float*)(ws + 40706048);
  float*  out    = (float*)d_out;

  prep_w<<<2048 * 9, 256, 0, stream>>>(w_ih, w_hh, Wtl);
  init_k<<<256, 256, 0, stream>>>(Xin, Xs, input, tau_h, tau_o, AlphaH,
                                  AlphaO, w_ho, WhoD);
  void* args[] = {(void*)&Wtl, (void*)&Xin, (void*)&Xs, (void*)&Po,
                  (void*)&WhoD, (void*)&AlphaH, (void*)&AlphaO, (void*)&out};
  hipLaunchCooperativeKernel((void*)rsnn_k, dim3(256), dim3(512), args, 0,
                             stream);
}

// Round 3
// 3195.697 us; speedup vs baseline: 1.0036x; 1.0036x over previous
//
#include <hip/hip_runtime.h>
#include <hip/hip_cooperative_groups.h>
#include <stdint.h>
#include <math.h>

namespace cg = cooperative_groups;

// ---------------------------------------------------------------------------
// RSNN forward, MI355X. EXACT integer hidden GEMM (absmax 0.0156): 27-bit
// fixed-point weights -> 3 signed base-256 i8 digit planes, binary
// activations, i32 MFMA, exact int64 recombination, single fp32 round,
// fp32 program-order decay.
// Round-13: round-12 persistent cooperative kernel + amdgpu_waves_per_eu(2,2)
// to PIN the VGPR budget at 256/wave. Round-12 failed because
// __launch_bounds__(512,2) only sets a MINIMUM occupancy -- the backend
// targeted 4 waves/EU (128 regs) and spilled the 144-reg resident weight
// block to scratch (FETCH_SIZE 1.3 GB/dispatch, 3.1 ms). With min=max=2 the
// budget is 256: breg 144 + acc 48 + a 16 + state ~20 fits with headroom.
// Everything else identical to round-12 (bit-identical numerics).
// ---------------------------------------------------------------------------

#define B_   256
#define T_   50
#define I_   1024
#define H_   2048
#define O_   20
#define XIN_T  262144    // input bytes per t: 4 bg * 16 kx * 4096
#define XS_BUF 524288    // one spike buffer: 4 bg * 32 kx * 4096
#define WNT 294912       // weight bytes per nt (32 cols): 3 * 48 * 2048
#define WPL 98304        // bytes per plane within an nt

typedef __attribute__((ext_vector_type(4))) int intx4;
typedef long long ll_t;

// ---------------------------------------------------------------------------
// Weight prep: digit p of W(n,kk) -> [nt 64][p 3][kx 48][row 32][64B]
// ---------------------------------------------------------------------------
__device__ __forceinline__ int digit_of(float v, int p) {
  int W = (int)rintf(v * 134217728.0f);   // exact: |W| <= 2^22
  int c0 = ((W + 128) & 255) - 128;
  int W1 = (W - c0) >> 8;
  int c1 = ((W1 + 128) & 255) - 128;
  int W2 = (W1 - c1) >> 8;
  return (p == 0) ? c0 : (p == 1) ? c1 : W2;
}

__global__ void prep_w(const float* __restrict__ w_ih,
                       const float* __restrict__ w_hh,
                       int8_t* __restrict__ Wtl) {
  int blk = blockIdx.x;
  int n = blk / 9, kg = blk % 9;
  int k9 = (kg * 256 + (int)threadIdx.x) * 4;   // [0, 9216)
  int p = k9 / 3072, kk = k9 % 3072;
  const float* src = (kk < 1024) ? (w_ih + n * I_ + kk)
                                 : (w_hh + n * H_ + (kk - 1024));
  float4 v = *(const float4*)src;
  int d0 = digit_of(v.x, p) & 255;
  int d1 = digit_of(v.y, p) & 255;
  int d2 = digit_of(v.z, p) & 255;
  int d3 = digit_of(v.w, p) & 255;
  int packed = d0 | (d1 << 8) | (d2 << 16) | (d3 << 24);
  size_t off = (size_t)(n >> 5) * WNT + (size_t)p * WPL + (kk >> 6) * 2048 +
               (n & 31) * 64 + (kk & 63);
  *(int*)(Wtl + off) = packed;
}

// ---------------------------------------------------------------------------
// Init: pack input for ALL t, zero spike buf0, tables.
// ---------------------------------------------------------------------------
__global__ void init_k(int8_t* __restrict__ Xin, int8_t* __restrict__ Xs,
                       const float* __restrict__ input,
                       const float* __restrict__ tau_h,
                       const float* __restrict__ tau_o,
                       float* __restrict__ AlphaH, float* __restrict__ AlphaO,
                       const float* __restrict__ w_ho,
                       double* __restrict__ WhoD) {
  int id = blockIdx.x * 256 + threadIdx.x;   // [0, 65536)
  {
    int b = id >> 8, i4 = (id & 255) * 4;
    for (int t = 0; t < T_; ++t) {
      float4 v = *(const float4*)(input + ((size_t)(b * T_ + t) << 10) + i4);
      uchar4 pk;
      pk.x = v.x > 0.5f ? 1 : 0;
      pk.y = v.y > 0.5f ? 1 : 0;
      pk.z = v.z > 0.5f ? 1 : 0;
      pk.w = v.w > 0.5f ? 1 : 0;
      *(uchar4*)(Xin + (size_t)t * XIN_T + (b >> 6) * 65536 + (i4 >> 6) * 4096 +
                 (b & 63) * 64 + (i4 & 63)) = pk;
    }
  }
  *(double*)(Xs + (size_t)id * 8) = 0.0;        // zero spike buf0
  if (id < 64 * O_ * 32) {                      // WhoD [nt 64][o 20][hl 32]
    int nt = id / 640, rem = id % 640, o = rem / 32, hl = rem & 31;
    WhoD[id] = (double)w_ho[o * H_ + nt * 32 + hl];
  }
  if (id < H_) AlphaH[id] = (float)exp((double)(-1.0f / tau_h[id]));
  if (id < O_) AlphaO[id] = (float)exp((double)(-1.0f / tau_o[id]));
}

// ---------------------------------------------------------------------------
// Persistent kernel: 256 blocks x 512 threads, 1 block/CU, 2 waves/SIMD
// pinned (256-VGPR budget). Block (nt in [0,64), mg in [0,4)): 64 batch x
// 32 h, full K, all 50 steps. Wave k = K-eighth (6 slabs), 4fr x 2fc x 3p.
// ---------------------------------------------------------------------------
__global__ __launch_bounds__(512)
__attribute__((amdgpu_waves_per_eu(2, 2))) void rsnn_k(
    const int8_t* __restrict__ Wtl, const int8_t* __restrict__ Xin,
    int8_t* __restrict__ Xs, double* __restrict__ Po,
    const double* __restrict__ WhoD, const float* __restrict__ AlphaH,
    const float* __restrict__ AlphaO, float* __restrict__ out) {
  cg::grid_group grid = cg::this_grid();
  __shared__ double WhoL[640];
  __shared__ __align__(16) int8_t red[98304];   // [wave 8][frag 12][lane 64][16B]
  __shared__ int8_t spk_lT[2048];               // [h 32][b 64]

  const int j = blockIdx.x;                     // [0,256)
  const int nt = (j & 7) * 8 + ((j >> 3) & 7);  // same nt -> same j%8 (XCD)
  const int mg = j >> 6;                        // 64-batch group [0,4)
  const int tid = threadIdx.x;
  const int l = tid & 63, k = tid >> 6;
  const int r_ = l & 15, q = l >> 4;

  for (int i = tid; i < 640; i += 512) WhoL[i] = WhoD[nt * 640 + i];

  // fixed per-thread epilogue coordinates (wave role is static)
  const int fr_e = (k < 4) ? (k >> 1) : (2 + ((k - 4) >> 1));
  const int fc_e = k & 1;
  const int h_e = nt * 32 + fc_e * 16 + r_;
  const float alpha_e = AlphaH[h_e];
  const float alphaO_r = (l < O_) ? AlphaO[l] : 0.f;

  // persistent per-thread state
  float hm[4] = {0.f, 0.f, 0.f, 0.f};          // membrane, 4 batch rows
  float om = 0.f, osp = 0.f, osu = 0.f, mo = 0.f;  // wave-7 lanes l<20

  // resident weights: K-eighth of the 32-h panel, [slab 6][fc 2][p 3]
  const int u0 = k * 6;
  const int8_t* Bw = Wtl + (size_t)nt * WNT + r_ * 64 + q * 16;
  intx4 breg[6][2][3];
#pragma unroll
  for (int i = 0; i < 6; ++i)
#pragma unroll
    for (int p = 0; p < 3; ++p)
#pragma unroll
      for (int fc = 0; fc < 2; ++fc)
        breg[i][fc][p] =
            *(const intx4*)(Bw + (size_t)(u0 + i) * 2048 + p * WPL + fc * 1024);

  const int arow = r_ * 64 + q * 16;

#define REDP(w, idx) (red + (((w) * 12 + (idx)) * 64 + l) * 16)

  for (int t = 0; t <= T_; ++t) {
    grid.sync();   // spikes(t), Po(t-1) visible across XCDs

    if (t < T_) {
      const int8_t* Ain = Xin + (size_t)t * XIN_T + mg * 65536 + arow;
      const int8_t* Asp = Xs + (size_t)(t & 1) * XS_BUF + mg * 131072 + arow;
      int8_t* Xw = Xs + (size_t)((t + 1) & 1) * XS_BUF;

      intx4 acc[4][2][3];
#pragma unroll
      for (int fr = 0; fr < 4; ++fr)
#pragma unroll
        for (int fc = 0; fc < 2; ++fc)
#pragma unroll
          for (int p = 0; p < 3; ++p) acc[fr][fc][p] = (intx4){0, 0, 0, 0};

      // ---- K-loop: 6 slabs, A loads only (B resident) ----
#pragma unroll
      for (int i = 0; i < 6; ++i) {
        const int u = u0 + i;
        const int8_t* ap =
            (u < 16) ? (Ain + u * 4096) : (Asp + (u - 16) * 4096);
        intx4 a0 = *(const intx4*)ap;
        intx4 a1 = *(const intx4*)(ap + 1024);
        intx4 a2 = *(const intx4*)(ap + 2048);
        intx4 a3 = *(const intx4*)(ap + 3072);
#pragma unroll
        for (int p = 0; p < 3; ++p)
#pragma unroll
          for (int fc = 0; fc < 2; ++fc) {
            acc[0][fc][p] = __builtin_amdgcn_mfma_i32_16x16x64_i8(
                a0, breg[i][fc][p], acc[0][fc][p], 0, 0, 0);
            acc[1][fc][p] = __builtin_amdgcn_mfma_i32_16x16x64_i8(
                a1, breg[i][fc][p], acc[1][fc][p], 0, 0, 0);
            acc[2][fc][p] = __builtin_amdgcn_mfma_i32_16x16x64_i8(
                a2, breg[i][fc][p], acc[2][fc][p], 0, 0, 0);
            acc[3][fc][p] = __builtin_amdgcn_mfma_i32_16x16x64_i8(
                a3, breg[i][fc][p], acc[3][fc][p], 0, 0, 0);
          }
      }

      // ---- epilogue body: exact recombine, reg-resident membrane ----
      auto epilogue = [&](intx4 s0, intx4 s1, intx4 s2) {
        unsigned spkpack = 0;
#pragma unroll
        for (int jj = 0; jj < 4; ++jj) {
          ll_t Sv = (ll_t)s0[jj] + ((ll_t)s1[jj] << 8) + ((ll_t)s2[jj] << 16);
          float M = (float)((double)Sv * 7.450580596923828125e-9);  // * 2^-27
          float hp = hm[jj];
          float spf = (hp - 0.3f) > 0.f ? 1.f : 0.f;
          float hmn = M + hp * alpha_e * (1.0f - spf);   // fp32 program order
          hm[jj] = hmn;
          unsigned spk = (hmn - 0.3f) > 0.f ? 1u : 0u;
          const int brl = fr_e * 16 + q * 4 + jj;        // batch row [0,64)
          Xw[mg * 131072 + (h_e >> 6) * 4096 + brl * 64 + (h_e & 63)] =
              (int8_t)spk;
          spkpack |= spk << (8 * jj);
        }
        *(unsigned*)(spk_lT + (fc_e * 16 + r_) * 64 + fr_e * 16 + q * 4) =
            spkpack;
      };

      // ---- Round A: fragments fr 0..1 -> waves 0..3 merge + epilogue ----
#pragma unroll
      for (int fr = 0; fr < 2; ++fr)
#pragma unroll
        for (int fc = 0; fc < 2; ++fc)
#pragma unroll
          for (int p = 0; p < 3; ++p)
            *(intx4*)REDP(k, (fr * 2 + fc) * 3 + p) = acc[fr][fc][p];
      __syncthreads();
      if (k < 4) {
        const int base = (fr_e * 2 + fc_e) * 3;
        intx4 s0 = (intx4){0, 0, 0, 0}, s1 = s0, s2 = s0;
#pragma unroll
        for (int w = 0; w < 8; ++w) {
          s0 = s0 + *(const intx4*)REDP(w, base + 0);
          s1 = s1 + *(const intx4*)REDP(w, base + 1);
          s2 = s2 + *(const intx4*)REDP(w, base + 2);
        }
        epilogue(s0, s1, s2);
      }
      __syncthreads();
      // ---- Round B: fragments fr 2..3 -> waves 4..7 merge + epilogue ----
#pragma unroll
      for (int fr = 0; fr < 2; ++fr)
#pragma unroll
        for (int fc = 0; fc < 2; ++fc)
#pragma unroll
          for (int p = 0; p < 3; ++p)
            *(intx4*)REDP(k, (fr * 2 + fc) * 3 + p) = acc[2 + fr][fc][p];
      __syncthreads();
      if (k >= 4) {
        const int base = ((fr_e - 2) * 2 + fc_e) * 3;
        intx4 s0 = (intx4){0, 0, 0, 0}, s1 = s0, s2 = s0;
#pragma unroll
        for (int w = 0; w < 8; ++w) {
          s0 = s0 + *(const intx4*)REDP(w, base + 0);
          s1 = s1 + *(const intx4*)REDP(w, base + 1);
          s2 = s2 + *(const intx4*)REDP(w, base + 2);
        }
        epilogue(s0, s1, s2);
      }
      __syncthreads();

      // ---- o-partials (waves 0-3): 32-h double dot -> Po[t&1][b][nt][o] ----
      if (tid < 256) {
        const int bl = tid >> 2, og = (tid & 3) * 5;
        const double* W0 = WhoL + og * 32;
        double a0 = 0, a1 = 0, a2 = 0, a3 = 0, a4 = 0;
#pragma unroll
        for (int hl = 0; hl < 32; ++hl) {
          double m = (double)spk_lT[hl * 64 + bl];
          a0 += m * W0[hl];
          a1 += m * W0[32 + hl];
          a2 += m * W0[64 + hl];
          a3 += m * W0[96 + hl];
          a4 += m * W0[128 + hl];
        }
        double* dst =
            Po + ((size_t)((t & 1) * 256 + mg * 64 + bl) * 64 + nt) * 20 + og;
        dst[0] = a0; dst[1] = a1; dst[2] = a2; dst[3] = a3; dst[4] = a4;
      }
    }

    // ---- head: o-phase for step t-1 (wave 7, batch j); t=50 -> final+out --
    if (k == 7 && t > 0) {
      float m = -3.0e38f;
      if (l < O_) {
        const double* pp =
            Po + ((size_t)(((t - 1) & 1) * 256 + j) * 64) * 20 + l;
        double s = 0.0;
#pragma unroll
        for (int n2 = 0; n2 < 64; ++n2) s += pp[n2 * 20];
        m = om * alphaO_r * (1.0f - osp) + (float)s;
      }
      float mx = m;
#pragma unroll
      for (int off = 16; off > 0; off >>= 1)
        mx = fmaxf(mx, __shfl_xor(mx, off, 32));
      float eo = (l < O_) ? expf(m - mx) : 0.f;
      float se = eo;
#pragma unroll
      for (int off = 16; off > 0; off >>= 1) se += __shfl_xor(se, off, 32);
      if (l < O_) {
        float sp = (m - 0.3f) > 0.f ? 1.f : 0.f;
        if (t < T_) {
          om = m; osp = sp; osu += sp; mo += eo / se;
        } else {
          out[j * O_ + l] = (osu + sp) / 50.0f;
          out[B_ * O_ + j * O_ + l] = mo + eo / se;
        }
      }
    }
  }
#undef REDP
}

// ---------------------------------------------------------------------------
extern "C" void kernel_launch(void* const* d_in, const int* in_sizes, int n_in,
                              void* d_out, int out_size, void* d_ws, size_t ws_size,
                              hipStream_t stream) {
  const float* input = (const float*)d_in[0];
  const float* w_ih  = (const float*)d_in[1];
  const float* w_hh  = (const float*)d_in[2];
  const float* w_ho  = (const float*)d_in[3];
  const float* tau_h = (const float*)d_in[4];
  const float* tau_o = (const float*)d_in[5];

  char* ws = (char*)d_ws;
  // layout (bytes):
  // Wtl    @ 0          18,874,368
  // Xin    @ 18874368   13,107,200
  // Xs     @ 31981568    1,048,576
  // Po     @ 33030144    5,242,880   (2 x 256 x 64 x 20 doubles)
  // WhoD   @ 40370176      327,680
  // AlphaH @ 40697856        8,192
  // AlphaO @ 40706048          128
  int8_t* Wtl    = (int8_t*)(ws);
  int8_t* Xin    = (int8_t*)(ws + 18874368);
  int8_t* Xs     = (int8_t*)(ws + 31981568);
  double* Po     = (double*)(ws + 33030144);
  double* WhoD   = (double*)(ws + 40370176);
  float*  AlphaH = (float*)(ws + 40697856);
  float*  AlphaO = (float*)(ws + 40706048);
  float*  out    = (float*)d_out;

  prep_w<<<2048 * 9, 256, 0, stream>>>(w_ih, w_hh, Wtl);
  init_k<<<256, 256, 0, stream>>>(Xin, Xs, input, tau_h, tau_o, AlphaH,
                                  AlphaO, w_ho, WhoD);
  void* args[] = {(void*)&Wtl, (void*)&Xin, (void*)&Xs, (void*)&Po,
                  (void*)&WhoD, (void*)&AlphaH, (void*)&AlphaO, (void*)&out};
  hipLaunchCooperativeKernel((void*)rsnn_k, dim3(256), dim3(512), args, 0,
                             stream);
}

// Round 4
// 3040.763 us; speedup vs baseline: 1.0547x; 1.0510x over previous
//
#include <hip/hip_runtime.h>
#include <hip/hip_cooperative_groups.h>
#include <stdint.h>
#include <math.h>

namespace cg = cooperative_groups;

// ---------------------------------------------------------------------------
// RSNN forward, MI355X. EXACT integer hidden GEMM (absmax 0.0156): 27-bit
// fixed-point weights -> 3 signed base-256 i8 digit planes, binary
// activations, i32 MFMA, exact int64 recombination, single fp32 round,
// fp32 program-order decay.
// Round-14: persistent cooperative kernel that FITS the 128-VGPR budget the
// compiler pins (rounds 12/13: 144-reg resident weights spilled -> 1.3 GB
// scratch traffic, 3.1 ms). New wave split: kb=k&1 picks 32-batch half,
// kq=k>>1 picks K-quarter (12 slabs). Live set: acc[2][2][3]=48 + A-dbuf 16
// + B-dbuf 48 ~= 112 regs -> no spill. B streamed from L2 (panel 2x/CU/step
// = 590 KB ~= 2 us). Single-round LDS merge (2 barriers/step), epilogue
// parallel on all 8 waves. Persistence keeps: no launch gaps, reg-resident
// membrane hm[4] + o-state, WhoL once, final fold at t=50.
// ---------------------------------------------------------------------------

#define B_   256
#define T_   50
#define I_   1024
#define H_   2048
#define O_   20
#define XIN_T  262144    // input bytes per t: 4 bg * 16 kx * 4096
#define XS_BUF 524288    // one spike buffer: 4 bg * 32 kx * 4096
#define WNT 294912       // weight bytes per nt (32 cols): 3 * 48 * 2048
#define WPL 98304        // bytes per plane within an nt

typedef __attribute__((ext_vector_type(4))) int intx4;
typedef long long ll_t;

// ---------------------------------------------------------------------------
// Weight prep: digit p of W(n,kk) -> [nt 64][p 3][kx 48][row 32][64B]
// ---------------------------------------------------------------------------
__device__ __forceinline__ int digit_of(float v, int p) {
  int W = (int)rintf(v * 134217728.0f);   // exact: |W| <= 2^22
  int c0 = ((W + 128) & 255) - 128;
  int W1 = (W - c0) >> 8;
  int c1 = ((W1 + 128) & 255) - 128;
  int W2 = (W1 - c1) >> 8;
  return (p == 0) ? c0 : (p == 1) ? c1 : W2;
}

__global__ void prep_w(const float* __restrict__ w_ih,
                       const float* __restrict__ w_hh,
                       int8_t* __restrict__ Wtl) {
  int blk = blockIdx.x;
  int n = blk / 9, kg = blk % 9;
  int k9 = (kg * 256 + (int)threadIdx.x) * 4;   // [0, 9216)
  int p = k9 / 3072, kk = k9 % 3072;
  const float* src = (kk < 1024) ? (w_ih + n * I_ + kk)
                                 : (w_hh + n * H_ + (kk - 1024));
  float4 v = *(const float4*)src;
  int d0 = digit_of(v.x, p) & 255;
  int d1 = digit_of(v.y, p) & 255;
  int d2 = digit_of(v.z, p) & 255;
  int d3 = digit_of(v.w, p) & 255;
  int packed = d0 | (d1 << 8) | (d2 << 16) | (d3 << 24);
  size_t off = (size_t)(n >> 5) * WNT + (size_t)p * WPL + (kk >> 6) * 2048 +
               (n & 31) * 64 + (kk & 63);
  *(int*)(Wtl + off) = packed;
}

// ---------------------------------------------------------------------------
// Init: pack input for ALL t, zero spike buf0, tables.
// ---------------------------------------------------------------------------
__global__ void init_k(int8_t* __restrict__ Xin, int8_t* __restrict__ Xs,
                       const float* __restrict__ input,
                       const float* __restrict__ tau_h,
                       const float* __restrict__ tau_o,
                       float* __restrict__ AlphaH, float* __restrict__ AlphaO,
                       const float* __restrict__ w_ho,
                       double* __restrict__ WhoD) {
  int id = blockIdx.x * 256 + threadIdx.x;   // [0, 65536)
  {
    int b = id >> 8, i4 = (id & 255) * 4;
    for (int t = 0; t < T_; ++t) {
      float4 v = *(const float4*)(input + ((size_t)(b * T_ + t) << 10) + i4);
      uchar4 pk;
      pk.x = v.x > 0.5f ? 1 : 0;
      pk.y = v.y > 0.5f ? 1 : 0;
      pk.z = v.z > 0.5f ? 1 : 0;
      pk.w = v.w > 0.5f ? 1 : 0;
      *(uchar4*)(Xin + (size_t)t * XIN_T + (b >> 6) * 65536 + (i4 >> 6) * 4096 +
                 (b & 63) * 64 + (i4 & 63)) = pk;
    }
  }
  *(double*)(Xs + (size_t)id * 8) = 0.0;        // zero spike buf0
  if (id < 64 * O_ * 32) {                      // WhoD [nt 64][o 20][hl 32]
    int nt = id / 640, rem = id % 640, o = rem / 32, hl = rem & 31;
    WhoD[id] = (double)w_ho[o * H_ + nt * 32 + hl];
  }
  if (id < H_) AlphaH[id] = (float)exp((double)(-1.0f / tau_h[id]));
  if (id < O_) AlphaO[id] = (float)exp((double)(-1.0f / tau_o[id]));
}

// ---------------------------------------------------------------------------
// Persistent kernel: 256 blocks x 512 threads (1/CU, 2 waves/SIMD).
// Block (nt in [0,64), mg in [0,4)): 64 batch x 32 h, full K, all 50 steps.
// Wave k: kb=k&1 -> 32-batch half, kq=k>>1 -> K-quarter (12 slabs).
// Per wave: acc[2fr][2fc][3p], epilogue combo (fr_e=kq>>1, fc_e=kq&1).
// ---------------------------------------------------------------------------
__global__ __launch_bounds__(512, 2) void rsnn_k(
    const int8_t* __restrict__ Wtl, const int8_t* __restrict__ Xin,
    int8_t* __restrict__ Xs, double* __restrict__ Po,
    const double* __restrict__ WhoD, const float* __restrict__ AlphaH,
    const float* __restrict__ AlphaO, float* __restrict__ out) {
  cg::grid_group grid = cg::this_grid();
  __shared__ double WhoL[640];
  __shared__ __align__(16) int8_t red[98304];   // [wave 8][frag 12][lane 64][16B]
  __shared__ int8_t spk_lT[2048];               // [h 32][b 64]

  const int j = blockIdx.x;                     // [0,256)
  const int nt = (j & 7) * 8 + ((j >> 3) & 7);  // same nt -> same j%8 (XCD)
  const int mg = j >> 6;                        // 64-batch group [0,4)
  const int tid = threadIdx.x;
  const int l = tid & 63, k = tid >> 6;
  const int r_ = l & 15, q = l >> 4;
  const int kb = k & 1, kq = k >> 1;

  for (int i = tid; i < 640; i += 512) WhoL[i] = WhoD[nt * 640 + i];

  // fixed per-thread epilogue coordinates (wave role is static)
  const int fr_e = kq >> 1;                     // fragment-row within kb half
  const int fc_e = kq & 1;
  const int h_e = nt * 32 + fc_e * 16 + r_;
  const float alpha_e = AlphaH[h_e];
  const float alphaO_r = (l < O_) ? AlphaO[l] : 0.f;

  // persistent per-thread state
  float hm[4] = {0.f, 0.f, 0.f, 0.f};          // membrane, 4 batch rows
  float om = 0.f, osp = 0.f, osu = 0.f, mo = 0.f;  // wave-7 lanes l<20

  const int u0 = kq * 12;                       // K-quarter: 12 slabs
  const int8_t* Bw = Wtl + (size_t)nt * WNT + r_ * 64 + q * 16;
  const int arow = r_ * 64 + q * 16;

#define REDP(w, idx) (red + (((w) * 12 + (idx)) * 64 + l) * 16)

  for (int t = 0; t <= T_; ++t) {
    grid.sync();   // spikes(t), Po(t-1) visible across XCDs

    if (t < T_) {
      const int8_t* Ain =
          Xin + (size_t)t * XIN_T + mg * 65536 + kb * 2048 + arow;
      const int8_t* Asp =
          Xs + (size_t)(t & 1) * XS_BUF + mg * 131072 + kb * 2048 + arow;
      int8_t* Xw = Xs + (size_t)((t + 1) & 1) * XS_BUF;

      intx4 acc[2][2][3];
#pragma unroll
      for (int fr = 0; fr < 2; ++fr)
#pragma unroll
        for (int fc = 0; fc < 2; ++fc)
#pragma unroll
          for (int p = 0; p < 3; ++p) acc[fr][fc][p] = (intx4){0, 0, 0, 0};

      // ---- K-loop: 12 slabs, depth-1 rotation (A dbuf 16 + B dbuf 48) ----
      intx4 a[2][2], b[2][2][3];
      {
        const int8_t* ap =
            (u0 < 16) ? (Ain + u0 * 4096) : (Asp + (u0 - 16) * 4096);
        a[0][0] = *(const intx4*)ap;
        a[0][1] = *(const intx4*)(ap + 1024);
        const int8_t* bp = Bw + (size_t)u0 * 2048;
#pragma unroll
        for (int p = 0; p < 3; ++p)
#pragma unroll
          for (int fc = 0; fc < 2; ++fc)
            b[0][fc][p] = *(const intx4*)(bp + p * WPL + fc * 1024);
      }
#pragma unroll
      for (int i = 0; i < 12; ++i) {
        const int cur = i & 1, nxt = cur ^ 1;
        if (i < 11) {
          const int un = u0 + i + 1;
          const int8_t* ap =
              (un < 16) ? (Ain + un * 4096) : (Asp + (un - 16) * 4096);
          a[nxt][0] = *(const intx4*)ap;
          a[nxt][1] = *(const intx4*)(ap + 1024);
          const int8_t* bp = Bw + (size_t)un * 2048;
#pragma unroll
          for (int p = 0; p < 3; ++p)
#pragma unroll
            for (int fc = 0; fc < 2; ++fc)
              b[nxt][fc][p] = *(const intx4*)(bp + p * WPL + fc * 1024);
        }
#pragma unroll
        for (int p = 0; p < 3; ++p)
#pragma unroll
          for (int fc = 0; fc < 2; ++fc) {
            acc[0][fc][p] = __builtin_amdgcn_mfma_i32_16x16x64_i8(
                a[cur][0], b[cur][fc][p], acc[0][fc][p], 0, 0, 0);
            acc[1][fc][p] = __builtin_amdgcn_mfma_i32_16x16x64_i8(
                a[cur][1], b[cur][fc][p], acc[1][fc][p], 0, 0, 0);
          }
      }

      // ---- single-round merge: all waves dump 12 frags, sum over 4 kq ----
#pragma unroll
      for (int fr = 0; fr < 2; ++fr)
#pragma unroll
        for (int fc = 0; fc < 2; ++fc)
#pragma unroll
          for (int p = 0; p < 3; ++p)
            *(intx4*)REDP(k, (fr * 2 + fc) * 3 + p) = acc[fr][fc][p];
      __syncthreads();
      {
        const int base = (fr_e * 2 + fc_e) * 3;
        intx4 s0 = (intx4){0, 0, 0, 0}, s1 = s0, s2 = s0;
#pragma unroll
        for (int w = 0; w < 4; ++w) {
          const int wi = w * 2 + kb;
          s0 = s0 + *(const intx4*)REDP(wi, base + 0);
          s1 = s1 + *(const intx4*)REDP(wi, base + 1);
          s2 = s2 + *(const intx4*)REDP(wi, base + 2);
        }
        // ---- epilogue: exact recombine, reg-resident membrane ----
        unsigned spkpack = 0;
#pragma unroll
        for (int jj = 0; jj < 4; ++jj) {
          ll_t Sv = (ll_t)s0[jj] + ((ll_t)s1[jj] << 8) + ((ll_t)s2[jj] << 16);
          float M = (float)((double)Sv * 7.450580596923828125e-9);  // * 2^-27
          float hp = hm[jj];
          float spf = (hp - 0.3f) > 0.f ? 1.f : 0.f;
          float hmn = M + hp * alpha_e * (1.0f - spf);   // fp32 program order
          hm[jj] = hmn;
          unsigned spk = (hmn - 0.3f) > 0.f ? 1u : 0u;
          const int brl = kb * 32 + fr_e * 16 + q * 4 + jj;  // batch row [0,64)
          Xw[mg * 131072 + (h_e >> 6) * 4096 + brl * 64 + (h_e & 63)] =
              (int8_t)spk;
          spkpack |= spk << (8 * jj);
        }
        *(unsigned*)(spk_lT + (fc_e * 16 + r_) * 64 + kb * 32 + fr_e * 16 +
                     q * 4) = spkpack;
      }
      __syncthreads();

      // ---- o-partials (waves 0-3): 32-h double dot -> Po[t&1][b][nt][o] ----
      if (tid < 256) {
        const int bl = tid >> 2, og = (tid & 3) * 5;
        const double* W0 = WhoL + og * 32;
        double a0 = 0, a1 = 0, a2 = 0, a3 = 0, a4 = 0;
#pragma unroll
        for (int hl = 0; hl < 32; ++hl) {
          double m = (double)spk_lT[hl * 64 + bl];
          a0 += m * W0[hl];
          a1 += m * W0[32 + hl];
          a2 += m * W0[64 + hl];
          a3 += m * W0[96 + hl];
          a4 += m * W0[128 + hl];
        }
        double* dst =
            Po + ((size_t)((t & 1) * 256 + mg * 64 + bl) * 64 + nt) * 20 + og;
        dst[0] = a0; dst[1] = a1; dst[2] = a2; dst[3] = a3; dst[4] = a4;
      }
    }

    // ---- head: o-phase for step t-1 (wave 7, batch j); t=50 -> final+out --
    if (k == 7 && t > 0) {
      float m = -3.0e38f;
      if (l < O_) {
        const double* pp =
            Po + ((size_t)(((t - 1) & 1) * 256 + j) * 64) * 20 + l;
        double s = 0.0;
#pragma unroll
        for (int n2 = 0; n2 < 64; ++n2) s += pp[n2 * 20];
        m = om * alphaO_r * (1.0f - osp) + (float)s;
      }
      float mx = m;
#pragma unroll
      for (int off = 16; off > 0; off >>= 1)
        mx = fmaxf(mx, __shfl_xor(mx, off, 32));
      float eo = (l < O_) ? expf(m - mx) : 0.f;
      float se = eo;
#pragma unroll
      for (int off = 16; off > 0; off >>= 1) se += __shfl_xor(se, off, 32);
      if (l < O_) {
        float sp = (m - 0.3f) > 0.f ? 1.f : 0.f;
        if (t < T_) {
          om = m; osp = sp; osu += sp; mo += eo / se;
        } else {
          out[j * O_ + l] = (osu + sp) / 50.0f;
          out[B_ * O_ + j * O_ + l] = mo + eo / se;
        }
      }
    }
  }
#undef REDP
}

// ---------------------------------------------------------------------------
extern "C" void kernel_launch(void* const* d_in, const int* in_sizes, int n_in,
                              void* d_out, int out_size, void* d_ws, size_t ws_size,
                              hipStream_t stream) {
  const float* input = (const float*)d_in[0];
  const float* w_ih  = (const float*)d_in[1];
  const float* w_hh  = (const float*)d_in[2];
  const float* w_ho  = (const float*)d_in[3];
  const float* tau_h = (const float*)d_in[4];
  const float* tau_o = (const float*)d_in[5];

  char* ws = (char*)d_ws;
  // layout (bytes):
  // Wtl    @ 0          18,874,368
  // Xin    @ 18874368   13,107,200
  // Xs     @ 31981568    1,048,576
  // Po     @ 33030144    5,242,880   (2 x 256 x 64 x 20 doubles)
  // WhoD   @ 40370176      327,680
  // AlphaH @ 40697856        8,192
  // AlphaO @ 40706048          128
  int8_t* Wtl    = (int8_t*)(ws);
  int8_t* Xin    = (int8_t*)(ws + 18874368);
  int8_t* Xs     = (int8_t*)(ws + 31981568);
  double* Po     = (double*)(ws + 33030144);
  double* WhoD   = (double*)(ws + 40370176);
  float*  AlphaH = (float*)(ws + 40697856);
  float*  AlphaO = (float*)(ws + 40706048);
  float*  out    = (float*)d_out;

  prep_w<<<2048 * 9, 256, 0, stream>>>(w_ih, w_hh, Wtl);
  init_k<<<256, 256, 0, stream>>>(Xin, Xs, input, tau_h, tau_o, AlphaH,
                                  AlphaO, w_ho, WhoD);
  void* args[] = {(void*)&Wtl, (void*)&Xin, (void*)&Xs, (void*)&Po,
                  (void*)&WhoD, (void*)&AlphaH, (void*)&AlphaO, (void*)&out};
  hipLaunchCooperativeKernel((void*)rsnn_k, dim3(256), dim3(512), args, 0,
                             stream);
}

// Round 5
// 1035.697 us; speedup vs baseline: 3.0966x; 2.9360x over previous
//
#include <hip/hip_runtime.h>
#include <stdint.h>
#include <math.h>

// ---------------------------------------------------------------------------
// RSNN forward, MI355X. EXACT integer hidden GEMM (absmax 0.0156): 27-bit
// fixed-point weights -> 3 signed base-256 i8 digit planes, binary
// activations, i32 MFMA, exact int64 recombination, single fp32 round,
// fp32 program-order decay.
// Round-15: per-step launches (persistence removed: rounds 12-14 showed
// grid.sync costs ~45 us/step -- all pipes idle at 3 ms regardless of
// spills). Keeps round-14's spill-free wave decomposition: 256 blocks x
// 512 threads, block = 64 batch x 32 h; wave k -> kb=k&1 (32-batch half),
// kq=k>>1 (K-quarter, 12 slabs). Live set acc[2][2][3]=48 + A-dbuf 16 +
// B-dbuf 48 ~= 112 < 128 VGPR -> no K-loop spill (round-11 ran 176 live on
// a 128 budget). Single-round LDS merge, 2 barriers/step, epilogue parallel
// on all 8 waves; head o-phase (t-1) on wave 7 overlaps o-partials.
// ---------------------------------------------------------------------------

#define B_   256
#define T_   50
#define I_   1024
#define H_   2048
#define O_   20
#define XIN_T  262144    // input bytes per t: 4 bg * 16 kx * 4096
#define XS_BUF 524288    // one spike buffer: 4 bg * 32 kx * 4096
#define WNT 294912       // weight bytes per nt (32 cols): 3 * 48 * 2048
#define WPL 98304        // bytes per plane within an nt

typedef __attribute__((ext_vector_type(4))) int intx4;
typedef long long ll_t;

// ---------------------------------------------------------------------------
// Weight prep: digit p of W(n,kk) -> [nt 64][p 3][kx 48][row 32][64B]
// ---------------------------------------------------------------------------
__device__ __forceinline__ int digit_of(float v, int p) {
  int W = (int)rintf(v * 134217728.0f);   // exact: |W| <= 2^22
  int c0 = ((W + 128) & 255) - 128;
  int W1 = (W - c0) >> 8;
  int c1 = ((W1 + 128) & 255) - 128;
  int W2 = (W1 - c1) >> 8;
  return (p == 0) ? c0 : (p == 1) ? c1 : W2;
}

__global__ void prep_w(const float* __restrict__ w_ih,
                       const float* __restrict__ w_hh,
                       int8_t* __restrict__ Wtl) {
  int blk = blockIdx.x;
  int n = blk / 9, kg = blk % 9;
  int k9 = (kg * 256 + (int)threadIdx.x) * 4;   // [0, 9216)
  int p = k9 / 3072, kk = k9 % 3072;
  const float* src = (kk < 1024) ? (w_ih + n * I_ + kk)
                                 : (w_hh + n * H_ + (kk - 1024));
  float4 v = *(const float4*)src;
  int d0 = digit_of(v.x, p) & 255;
  int d1 = digit_of(v.y, p) & 255;
  int d2 = digit_of(v.z, p) & 255;
  int d3 = digit_of(v.w, p) & 255;
  int packed = d0 | (d1 << 8) | (d2 << 16) | (d3 << 24);
  size_t off = (size_t)(n >> 5) * WNT + (size_t)p * WPL + (kk >> 6) * 2048 +
               (n & 31) * 64 + (kk & 63);
  *(int*)(Wtl + off) = packed;
}

// ---------------------------------------------------------------------------
// Init: pack input for ALL t, zero spike buf0 + Hm + o-state, tables.
// ---------------------------------------------------------------------------
__global__ void init_k(int8_t* __restrict__ Xin, int8_t* __restrict__ Xs,
                       float* __restrict__ Hm, const float* __restrict__ input,
                       const float* __restrict__ tau_h,
                       const float* __restrict__ tau_o,
                       float* __restrict__ AlphaH, float* __restrict__ AlphaO,
                       const float* __restrict__ w_ho, double* __restrict__ WhoD,
                       float* __restrict__ Om, float* __restrict__ Osp,
                       float* __restrict__ Osu, float* __restrict__ Mo) {
  int id = blockIdx.x * 256 + threadIdx.x;   // [0, 65536)
  {
    int b = id >> 8, i4 = (id & 255) * 4;
    for (int t = 0; t < T_; ++t) {
      float4 v = *(const float4*)(input + ((size_t)(b * T_ + t) << 10) + i4);
      uchar4 pk;
      pk.x = v.x > 0.5f ? 1 : 0;
      pk.y = v.y > 0.5f ? 1 : 0;
      pk.z = v.z > 0.5f ? 1 : 0;
      pk.w = v.w > 0.5f ? 1 : 0;
      *(uchar4*)(Xin + (size_t)t * XIN_T + (b >> 6) * 65536 + (i4 >> 6) * 4096 +
                 (b & 63) * 64 + (i4 & 63)) = pk;
    }
  }
  *(double*)(Xs + (size_t)id * 8) = 0.0;        // zero spike buf0
  *(float4*)(Hm + (size_t)id * 8) = make_float4(0.f, 0.f, 0.f, 0.f);
  *(float4*)(Hm + (size_t)id * 8 + 4) = make_float4(0.f, 0.f, 0.f, 0.f);
  if (id < 64 * O_ * 32) {                      // WhoD [nt 64][o 20][hl 32]
    int nt = id / 640, rem = id % 640, o = rem / 32, hl = rem & 31;
    WhoD[id] = (double)w_ho[o * H_ + nt * 32 + hl];
  }
  if (id < H_) AlphaH[id] = (float)exp((double)(-1.0f / tau_h[id]));
  if (id < O_) AlphaO[id] = (float)exp((double)(-1.0f / tau_o[id]));
  if (id < B_ * O_) {
    Om[id] = 0.f; Osp[id] = 0.f; Osu[id] = 0.f; Mo[id] = 0.f;
  }
}

// ---------------------------------------------------------------------------
// Per-step kernel: 256 blocks x 512 threads (1/CU, 2 waves/SIMD).
// Block (nt in [0,64), mg in [0,4)): 64 batch x 32 h, full K.
// Wave k: kb=k&1 -> 32-batch half, kq=k>>1 -> K-quarter (12 slabs).
// ---------------------------------------------------------------------------
__global__ __launch_bounds__(512, 2) void step_k(
    const int8_t* __restrict__ Wtl, const int8_t* __restrict__ Xin,
    int8_t* __restrict__ Xs, float* __restrict__ Hm, double* __restrict__ Po,
    const double* __restrict__ WhoD, const float* __restrict__ AlphaH,
    const float* __restrict__ AlphaO, float* __restrict__ Om,
    float* __restrict__ Osp, float* __restrict__ Osu, float* __restrict__ Mo,
    int t) {
  __shared__ double WhoL[640];
  __shared__ __align__(16) int8_t red[98304];   // [wave 8][frag 12][lane 64][16B]
  __shared__ int8_t spk_lT[2048];               // [h 32][b 64]

  const int j = blockIdx.x;                     // [0,256)
  const int nt = (j & 7) * 8 + ((j >> 3) & 7);  // same nt -> same j%8 (XCD)
  const int mg = j >> 6;                        // 64-batch group [0,4)
  const int tid = threadIdx.x;
  const int l = tid & 63, k = tid >> 6;
  const int r_ = l & 15, q = l >> 4;
  const int kb = k & 1, kq = k >> 1;

  for (int i = tid; i < 640; i += 512) WhoL[i] = WhoD[nt * 640 + i];

  // fixed per-thread epilogue coordinates (wave role is static)
  const int fr_e = kq >> 1;                     // fragment-row within kb half
  const int fc_e = kq & 1;
  const int h_e = nt * 32 + fc_e * 16 + r_;

  const int u0 = kq * 12;                       // K-quarter: 12 slabs
  const int8_t* Bw = Wtl + (size_t)nt * WNT + r_ * 64 + q * 16;
  const int arow = r_ * 64 + q * 16;

#define REDP(w, idx) (red + (((w) * 12 + (idx)) * 64 + l) * 16)

  const int8_t* Ain = Xin + (size_t)t * XIN_T + mg * 65536 + kb * 2048 + arow;
  const int8_t* Asp =
      Xs + (size_t)(t & 1) * XS_BUF + mg * 131072 + kb * 2048 + arow;
  int8_t* Xw = Xs + (size_t)((t + 1) & 1) * XS_BUF;

  intx4 acc[2][2][3];
#pragma unroll
  for (int fr = 0; fr < 2; ++fr)
#pragma unroll
    for (int fc = 0; fc < 2; ++fc)
#pragma unroll
      for (int p = 0; p < 3; ++p) acc[fr][fc][p] = (intx4){0, 0, 0, 0};

  // ---- K-loop: 12 slabs, depth-1 rotation (A dbuf 16 + B dbuf 48) ----
  intx4 a[2][2], b[2][2][3];
  {
    const int8_t* ap = (u0 < 16) ? (Ain + u0 * 4096) : (Asp + (u0 - 16) * 4096);
    a[0][0] = *(const intx4*)ap;
    a[0][1] = *(const intx4*)(ap + 1024);
    const int8_t* bp = Bw + (size_t)u0 * 2048;
#pragma unroll
    for (int p = 0; p < 3; ++p)
#pragma unroll
      for (int fc = 0; fc < 2; ++fc)
        b[0][fc][p] = *(const intx4*)(bp + p * WPL + fc * 1024);
  }
#pragma unroll
  for (int i = 0; i < 12; ++i) {
    const int cur = i & 1, nxt = cur ^ 1;
    if (i < 11) {
      const int un = u0 + i + 1;
      const int8_t* ap =
          (un < 16) ? (Ain + un * 4096) : (Asp + (un - 16) * 4096);
      a[nxt][0] = *(const intx4*)ap;
      a[nxt][1] = *(const intx4*)(ap + 1024);
      const int8_t* bp = Bw + (size_t)un * 2048;
#pragma unroll
      for (int p = 0; p < 3; ++p)
#pragma unroll
        for (int fc = 0; fc < 2; ++fc)
          b[nxt][fc][p] = *(const intx4*)(bp + p * WPL + fc * 1024);
    }
#pragma unroll
    for (int p = 0; p < 3; ++p)
#pragma unroll
      for (int fc = 0; fc < 2; ++fc) {
        acc[0][fc][p] = __builtin_amdgcn_mfma_i32_16x16x64_i8(
            a[cur][0], b[cur][fc][p], acc[0][fc][p], 0, 0, 0);
        acc[1][fc][p] = __builtin_amdgcn_mfma_i32_16x16x64_i8(
            a[cur][1], b[cur][fc][p], acc[1][fc][p], 0, 0, 0);
      }
  }

  // ---- single-round merge: all waves dump 12 frags, sum over 4 kq ----
#pragma unroll
  for (int fr = 0; fr < 2; ++fr)
#pragma unroll
    for (int fc = 0; fc < 2; ++fc)
#pragma unroll
      for (int p = 0; p < 3; ++p)
        *(intx4*)REDP(k, (fr * 2 + fc) * 3 + p) = acc[fr][fc][p];
  __syncthreads();
  {
    const int base = (fr_e * 2 + fc_e) * 3;
    intx4 s0 = (intx4){0, 0, 0, 0}, s1 = s0, s2 = s0;
#pragma unroll
    for (int w = 0; w < 4; ++w) {
      const int wi = w * 2 + kb;
      s0 = s0 + *(const intx4*)REDP(wi, base + 0);
      s1 = s1 + *(const intx4*)REDP(wi, base + 1);
      s2 = s2 + *(const intx4*)REDP(wi, base + 2);
    }
    // ---- epilogue: exact recombine, global membrane, spike write ----
    const float alpha = AlphaH[h_e];
    unsigned spkpack = 0;
#pragma unroll
    for (int jj = 0; jj < 4; ++jj) {
      ll_t Sv = (ll_t)s0[jj] + ((ll_t)s1[jj] << 8) + ((ll_t)s2[jj] << 16);
      float M = (float)((double)Sv * 7.450580596923828125e-9);  // * 2^-27
      const int brl = kb * 32 + fr_e * 16 + q * 4 + jj;  // batch row [0,64)
      const int idx = (mg * 64 + brl) * H_ + h_e;
      float hp = Hm[idx];
      float spf = (hp - 0.3f) > 0.f ? 1.f : 0.f;
      float hmn = M + hp * alpha * (1.0f - spf);   // fp32 program order
      Hm[idx] = hmn;
      unsigned spk = (hmn - 0.3f) > 0.f ? 1u : 0u;
      Xw[mg * 131072 + (h_e >> 6) * 4096 + brl * 64 + (h_e & 63)] =
          (int8_t)spk;
      spkpack |= spk << (8 * jj);
    }
    *(unsigned*)(spk_lT + (fc_e * 16 + r_) * 64 + kb * 32 + fr_e * 16 +
                 q * 4) = spkpack;
  }
  __syncthreads();

  // ---- o-partials (waves 0-3) || head o-phase for t-1 (wave 7) ----
  if (tid < 256) {
    const int bl = tid >> 2, og = (tid & 3) * 5;
    const double* W0 = WhoL + og * 32;
    double a0 = 0, a1 = 0, a2 = 0, a3 = 0, a4 = 0;
#pragma unroll
    for (int hl = 0; hl < 32; ++hl) {
      double m = (double)spk_lT[hl * 64 + bl];
      a0 += m * W0[hl];
      a1 += m * W0[32 + hl];
      a2 += m * W0[64 + hl];
      a3 += m * W0[96 + hl];
      a4 += m * W0[128 + hl];
    }
    double* dst =
        Po + ((size_t)((t & 1) * 256 + mg * 64 + bl) * 64 + nt) * 20 + og;
    dst[0] = a0; dst[1] = a1; dst[2] = a2; dst[3] = a3; dst[4] = a4;
  } else if (k == 7 && t > 0) {
    // head: o-phase for step t-1, batch j (overlaps o-partials)
    float m = -3.0e38f;
    if (l < O_) {
      const double* pp = Po + ((size_t)(((t - 1) & 1) * 256 + j) * 64) * 20 + l;
      double s = 0.0;
#pragma unroll
      for (int n2 = 0; n2 < 64; ++n2) s += pp[n2 * 20];
      m = Om[j * O_ + l] * AlphaO[l] * (1.0f - Osp[j * O_ + l]) + (float)s;
    }
    float mx = m;
#pragma unroll
    for (int off = 16; off > 0; off >>= 1)
      mx = fmaxf(mx, __shfl_xor(mx, off, 32));
    float eo = (l < O_) ? expf(m - mx) : 0.f;
    float se = eo;
#pragma unroll
    for (int off = 16; off > 0; off >>= 1) se += __shfl_xor(se, off, 32);
    if (l < O_) {
      float sp = (m - 0.3f) > 0.f ? 1.f : 0.f;
      Om[j * O_ + l] = m;
      Osp[j * O_ + l] = sp;
      Osu[j * O_ + l] += sp;
      Mo[j * O_ + l] += eo / se;
    }
  }
#undef REDP
}

// ---------------------------------------------------------------------------
// Final o-phase (t=49) + output write. 256 blocks x 64 threads.
// ---------------------------------------------------------------------------
__global__ void final_k(const double* __restrict__ Po,
                        const float* __restrict__ AlphaO,
                        const float* __restrict__ Om,
                        const float* __restrict__ Osp,
                        const float* __restrict__ Osu,
                        const float* __restrict__ Mo, float* __restrict__ out) {
  __shared__ float om_l[O_];
  const int j = blockIdx.x, tid = threadIdx.x;
  if (tid < O_) {
    const double* pp = Po + ((size_t)(256 + j) * 64) * 20 + tid;   // slot 1
    double s = 0.0;
#pragma unroll
    for (int n2 = 0; n2 < 64; ++n2) s += pp[n2 * 20];
    float r = (float)s;
    float m = Om[j * O_ + tid] * AlphaO[tid] * (1.0f - Osp[j * O_ + tid]) + r;
    om_l[tid] = m;
  }
  __syncthreads();
  if (tid < O_) {
    float m = om_l[tid];
    float mx = om_l[0];
#pragma unroll
    for (int o = 1; o < O_; ++o) mx = fmaxf(mx, om_l[o]);
    float se = 0.f;
#pragma unroll
    for (int o = 0; o < O_; ++o) se += expf(om_l[o] - mx);
    float sp = (m - 0.3f) > 0.f ? 1.f : 0.f;
    out[j * O_ + tid] = (Osu[j * O_ + tid] + sp) / 50.0f;
    out[B_ * O_ + j * O_ + tid] = Mo[j * O_ + tid] + expf(m - mx) / se;
  }
}

// ---------------------------------------------------------------------------
extern "C" void kernel_launch(void* const* d_in, const int* in_sizes, int n_in,
                              void* d_out, int out_size, void* d_ws, size_t ws_size,
                              hipStream_t stream) {
  const float* input = (const float*)d_in[0];
  const float* w_ih  = (const float*)d_in[1];
  const float* w_hh  = (const float*)d_in[2];
  const float* w_ho  = (const float*)d_in[3];
  const float* tau_h = (const float*)d_in[4];
  const float* tau_o = (const float*)d_in[5];

  char* ws = (char*)d_ws;
  // layout (bytes):
  // Wtl    @ 0          18,874,368
  // Xin    @ 18874368   13,107,200
  // Xs     @ 31981568    1,048,576
  // Po     @ 33030144    5,242,880   (2 x 256 x 64 x 20 doubles)
  // Hm     @ 38273024    2,097,152
  // WhoD   @ 40370176      327,680
  // AlphaH @ 40697856        8,192
  // AlphaO @ 40706048          128
  // Om     @ 40706176       20,480  (then Osp, Osu, Mo)
  int8_t* Wtl    = (int8_t*)(ws);
  int8_t* Xin    = (int8_t*)(ws + 18874368);
  int8_t* Xs     = (int8_t*)(ws + 31981568);
  double* Po     = (double*)(ws + 33030144);
  float*  Hm     = (float*)(ws + 38273024);
  double* WhoD   = (double*)(ws + 40370176);
  float*  AlphaH = (float*)(ws + 40697856);
  float*  AlphaO = (float*)(ws + 40706048);
  float*  Om     = (float*)(ws + 40706176);
  float*  Osp    = (float*)(ws + 40726656);
  float*  Osu    = (float*)(ws + 40747136);
  float*  Mo     = (float*)(ws + 40767616);
  float*  out    = (float*)d_out;

  prep_w<<<2048 * 9, 256, 0, stream>>>(w_ih, w_hh, Wtl);
  init_k<<<256, 256, 0, stream>>>(Xin, Xs, Hm, input, tau_h, tau_o, AlphaH,
                                  AlphaO, w_ho, WhoD, Om, Osp, Osu, Mo);
  for (int t = 0; t < T_; ++t) {
    step_k<<<256, 512, 0, stream>>>(Wtl, Xin, Xs, Hm, Po, WhoD, AlphaH, AlphaO,
                                    Om, Osp, Osu, Mo, t);
  }
  final_k<<<256, 64, 0, stream>>>(Po, AlphaO, Om, Osp, Osu, Mo, out);
}

// Round 6
// 971.832 us; speedup vs baseline: 3.3001x; 1.0657x over previous
//
#include <hip/hip_runtime.h>
#include <stdint.h>
#include <math.h>

// ---------------------------------------------------------------------------
// RSNN forward, MI355X. EXACT integer hidden GEMM (absmax 0.0156): 27-bit
// fixed-point weights -> 3 signed base-256 i8 digit planes, binary
// activations, i32 MFMA, exact int64 recombination, single fp32 round,
// fp32 program-order decay.
// Round-16: fc-group x K-quarter wave split. 256 blocks x 512 threads
// (1/CU); block = 64 batch x 32 h. Wave k -> fcg=k>>2 (16 h-cols),
// kq=k&3 (12 slabs). Live set acc[4][3]=48 + A-dbuf 32 + B-dbuf 24 ~= 104
// < 128 VGPR -> no spill AND B panel read ONCE per CU (295 KB; round-15's
// kb-split read it twice = +2.2 us/step, the measured regression vs r11).
// A read by fcg-twins (384 KB streamed, 196 unique, partial L1 hits).
// Single-round LDS merge; epilogue on ALL 8 waves (combo fr_e=k&3,
// fc_e=k>>2). Hm re-laid out [h][b]: membrane update = 1 float4 load +
// 1 float4 store (was 4 scattered 4B round-trips). 2 barriers/step.
// ---------------------------------------------------------------------------

#define B_   256
#define T_   50
#define I_   1024
#define H_   2048
#define O_   20
#define XIN_T  262144    // input bytes per t: 4 bg * 16 kx * 4096
#define XS_BUF 524288    // one spike buffer: 4 bg * 32 kx * 4096
#define WNT 294912       // weight bytes per nt (32 cols): 3 * 48 * 2048
#define WPL 98304        // bytes per plane within an nt

typedef __attribute__((ext_vector_type(4))) int intx4;
typedef long long ll_t;

// ---------------------------------------------------------------------------
// Weight prep: digit p of W(n,kk) -> [nt 64][p 3][kx 48][row 32][64B]
// ---------------------------------------------------------------------------
__device__ __forceinline__ int digit_of(float v, int p) {
  int W = (int)rintf(v * 134217728.0f);   // exact: |W| <= 2^22
  int c0 = ((W + 128) & 255) - 128;
  int W1 = (W - c0) >> 8;
  int c1 = ((W1 + 128) & 255) - 128;
  int W2 = (W1 - c1) >> 8;
  return (p == 0) ? c0 : (p == 1) ? c1 : W2;
}

__global__ void prep_w(const float* __restrict__ w_ih,
                       const float* __restrict__ w_hh,
                       int8_t* __restrict__ Wtl) {
  int blk = blockIdx.x;
  int n = blk / 9, kg = blk % 9;
  int k9 = (kg * 256 + (int)threadIdx.x) * 4;   // [0, 9216)
  int p = k9 / 3072, kk = k9 % 3072;
  const float* src = (kk < 1024) ? (w_ih + n * I_ + kk)
                                 : (w_hh + n * H_ + (kk - 1024));
  float4 v = *(const float4*)src;
  int d0 = digit_of(v.x, p) & 255;
  int d1 = digit_of(v.y, p) & 255;
  int d2 = digit_of(v.z, p) & 255;
  int d3 = digit_of(v.w, p) & 255;
  int packed = d0 | (d1 << 8) | (d2 << 16) | (d3 << 24);
  size_t off = (size_t)(n >> 5) * WNT + (size_t)p * WPL + (kk >> 6) * 2048 +
               (n & 31) * 64 + (kk & 63);
  *(int*)(Wtl + off) = packed;
}

// ---------------------------------------------------------------------------
// Init: pack input for ALL t, zero spike buf0 + Hm + o-state, tables.
// ---------------------------------------------------------------------------
__global__ void init_k(int8_t* __restrict__ Xin, int8_t* __restrict__ Xs,
                       float* __restrict__ Hm, const float* __restrict__ input,
                       const float* __restrict__ tau_h,
                       const float* __restrict__ tau_o,
                       float* __restrict__ AlphaH, float* __restrict__ AlphaO,
                       const float* __restrict__ w_ho, double* __restrict__ WhoD,
                       float* __restrict__ Om, float* __restrict__ Osp,
                       float* __restrict__ Osu, float* __restrict__ Mo) {
  int id = blockIdx.x * 256 + threadIdx.x;   // [0, 65536)
  {
    int b = id >> 8, i4 = (id & 255) * 4;
    for (int t = 0; t < T_; ++t) {
      float4 v = *(const float4*)(input + ((size_t)(b * T_ + t) << 10) + i4);
      uchar4 pk;
      pk.x = v.x > 0.5f ? 1 : 0;
      pk.y = v.y > 0.5f ? 1 : 0;
      pk.z = v.z > 0.5f ? 1 : 0;
      pk.w = v.w > 0.5f ? 1 : 0;
      *(uchar4*)(Xin + (size_t)t * XIN_T + (b >> 6) * 65536 + (i4 >> 6) * 4096 +
                 (b & 63) * 64 + (i4 & 63)) = pk;
    }
  }
  *(double*)(Xs + (size_t)id * 8) = 0.0;        // zero spike buf0
  *(float4*)(Hm + (size_t)id * 8) = make_float4(0.f, 0.f, 0.f, 0.f);
  *(float4*)(Hm + (size_t)id * 8 + 4) = make_float4(0.f, 0.f, 0.f, 0.f);
  if (id < 64 * O_ * 32) {                      // WhoD [nt 64][o 20][hl 32]
    int nt = id / 640, rem = id % 640, o = rem / 32, hl = rem & 31;
    WhoD[id] = (double)w_ho[o * H_ + nt * 32 + hl];
  }
  if (id < H_) AlphaH[id] = (float)exp((double)(-1.0f / tau_h[id]));
  if (id < O_) AlphaO[id] = (float)exp((double)(-1.0f / tau_o[id]));
  if (id < B_ * O_) {
    Om[id] = 0.f; Osp[id] = 0.f; Osu[id] = 0.f; Mo[id] = 0.f;
  }
}

// ---------------------------------------------------------------------------
// Per-step kernel: 256 blocks x 512 threads (1/CU, 2 waves/SIMD).
// Block (nt in [0,64), mg in [0,4)): 64 batch x 32 h, full K.
// Wave k: fcg=k>>2 -> 16 h-col group, kq=k&3 -> K-quarter (12 slabs).
// ---------------------------------------------------------------------------
__global__ __launch_bounds__(512, 2) void step_k(
    const int8_t* __restrict__ Wtl, const int8_t* __restrict__ Xin,
    int8_t* __restrict__ Xs, float* __restrict__ Hm, double* __restrict__ Po,
    const double* __restrict__ WhoD, const float* __restrict__ AlphaH,
    const float* __restrict__ AlphaO, float* __restrict__ Om,
    float* __restrict__ Osp, float* __restrict__ Osu, float* __restrict__ Mo,
    int t) {
  __shared__ double WhoL[640];
  __shared__ __align__(16) int8_t red[98304];   // [wave 8][frag 12][lane 64][16B]
  __shared__ int8_t spk_lT[2048];               // [h 32][b 64]

  const int j = blockIdx.x;                     // [0,256)
  const int nt = (j & 7) * 8 + ((j >> 3) & 7);  // same nt -> same j%8 (XCD)
  const int mg = j >> 6;                        // 64-batch group [0,4)
  const int tid = threadIdx.x;
  const int l = tid & 63, k = tid >> 6;
  const int r_ = l & 15, q = l >> 4;
  const int fcg = k >> 2, kq = k & 3;

  for (int i = tid; i < 640; i += 512) WhoL[i] = WhoD[nt * 640 + i];

  // fixed per-thread epilogue coordinates (wave role is static)
  const int fr_e = k & 3;                       // fragment-row (16 batch rows)
  const int fc_e = k >> 2;                      // h-col half (== own fcg)
  const int h_e = nt * 32 + fc_e * 16 + r_;

  const int u0 = kq * 12;                       // K-quarter: 12 slabs
  const int8_t* Bw =
      Wtl + (size_t)nt * WNT + fcg * 1024 + r_ * 64 + q * 16;
  const int arow = r_ * 64 + q * 16;

#define REDP(w, idx) (red + (((w) * 12 + (idx)) * 64 + l) * 16)

  const int8_t* Ain = Xin + (size_t)t * XIN_T + mg * 65536 + arow;
  const int8_t* Asp = Xs + (size_t)(t & 1) * XS_BUF + mg * 131072 + arow;
  int8_t* Xw = Xs + (size_t)((t + 1) & 1) * XS_BUF;

  intx4 acc[4][3];   // [fr][p]
#pragma unroll
  for (int fr = 0; fr < 4; ++fr)
#pragma unroll
    for (int p = 0; p < 3; ++p) acc[fr][p] = (intx4){0, 0, 0, 0};

  // ---- K-loop: 12 slabs, depth-1 rotation (A dbuf 32 + B dbuf 24) ----
  intx4 a[2][4], b[2][3];
  {
    const int8_t* ap = (u0 < 16) ? (Ain + u0 * 4096) : (Asp + (u0 - 16) * 4096);
#pragma unroll
    for (int fr = 0; fr < 4; ++fr) a[0][fr] = *(const intx4*)(ap + fr * 1024);
    const int8_t* bp = Bw + (size_t)u0 * 2048;
#pragma unroll
    for (int p = 0; p < 3; ++p) b[0][p] = *(const intx4*)(bp + p * WPL);
  }
#pragma unroll
  for (int i = 0; i < 12; ++i) {
    const int cur = i & 1, nxt = cur ^ 1;
    if (i < 11) {
      const int un = u0 + i + 1;
      const int8_t* ap =
          (un < 16) ? (Ain + un * 4096) : (Asp + (un - 16) * 4096);
#pragma unroll
      for (int fr = 0; fr < 4; ++fr) a[nxt][fr] = *(const intx4*)(ap + fr * 1024);
      const int8_t* bp = Bw + (size_t)un * 2048;
#pragma unroll
      for (int p = 0; p < 3; ++p) b[nxt][p] = *(const intx4*)(bp + p * WPL);
    }
#pragma unroll
    for (int p = 0; p < 3; ++p)
#pragma unroll
      for (int fr = 0; fr < 4; ++fr)
        acc[fr][p] = __builtin_amdgcn_mfma_i32_16x16x64_i8(
            a[cur][fr], b[cur][p], acc[fr][p], 0, 0, 0);
  }

  // ---- single-round merge: dump 12 frags, sum over 4 same-fcg waves ----
#pragma unroll
  for (int fr = 0; fr < 4; ++fr)
#pragma unroll
    for (int p = 0; p < 3; ++p)
      *(intx4*)REDP(k, fr * 3 + p) = acc[fr][p];
  __syncthreads();
  {
    const int base = fr_e * 3;
    intx4 s0 = (intx4){0, 0, 0, 0}, s1 = s0, s2 = s0;
#pragma unroll
    for (int w = 0; w < 4; ++w) {
      const int wi = fc_e * 4 + w;
      s0 = s0 + *(const intx4*)REDP(wi, base + 0);
      s1 = s1 + *(const intx4*)REDP(wi, base + 1);
      s2 = s2 + *(const intx4*)REDP(wi, base + 2);
    }
    // ---- epilogue: exact recombine, [h][b] membrane (float4), spikes ----
    const float alpha = AlphaH[h_e];
    float* hp_ptr = Hm + h_e * 256 + mg * 64 + fr_e * 16 + q * 4;
    float4 hp4 = *(float4*)hp_ptr;
    float* hp = reinterpret_cast<float*>(&hp4);
    unsigned spkpack = 0;
#pragma unroll
    for (int jj = 0; jj < 4; ++jj) {
      ll_t Sv = (ll_t)s0[jj] + ((ll_t)s1[jj] << 8) + ((ll_t)s2[jj] << 16);
      float M = (float)((double)Sv * 7.450580596923828125e-9);  // * 2^-27
      float hpv = hp[jj];
      float spf = (hpv - 0.3f) > 0.f ? 1.f : 0.f;
      float hmn = M + hpv * alpha * (1.0f - spf);   // fp32 program order
      hp[jj] = hmn;
      unsigned spk = (hmn - 0.3f) > 0.f ? 1u : 0u;
      const int brl = fr_e * 16 + q * 4 + jj;       // batch row [0,64)
      Xw[mg * 131072 + (h_e >> 6) * 4096 + brl * 64 + (h_e & 63)] =
          (int8_t)spk;
      spkpack |= spk << (8 * jj);
    }
    *(float4*)hp_ptr = hp4;
    *(unsigned*)(spk_lT + (fc_e * 16 + r_) * 64 + fr_e * 16 + q * 4) =
        spkpack;
  }
  __syncthreads();

  // ---- o-partials (waves 0-3) || head o-phase for t-1 (wave 7) ----
  if (tid < 256) {
    const int bl = tid >> 2, og = (tid & 3) * 5;
    const double* W0 = WhoL + og * 32;
    double a0 = 0, a1 = 0, a2 = 0, a3 = 0, a4 = 0;
#pragma unroll
    for (int hl = 0; hl < 32; ++hl) {
      double m = (double)spk_lT[hl * 64 + bl];
      a0 += m * W0[hl];
      a1 += m * W0[32 + hl];
      a2 += m * W0[64 + hl];
      a3 += m * W0[96 + hl];
      a4 += m * W0[128 + hl];
    }
    double* dst =
        Po + ((size_t)((t & 1) * 256 + mg * 64 + bl) * 64 + nt) * 20 + og;
    dst[0] = a0; dst[1] = a1; dst[2] = a2; dst[3] = a3; dst[4] = a4;
  } else if (k == 7 && t > 0) {
    // head: o-phase for step t-1, batch j (overlaps o-partials)
    float m = -3.0e38f;
    if (l < O_) {
      const double* pp = Po + ((size_t)(((t - 1) & 1) * 256 + j) * 64) * 20 + l;
      double s = 0.0;
#pragma unroll
      for (int n2 = 0; n2 < 64; ++n2) s += pp[n2 * 20];
      m = Om[j * O_ + l] * AlphaO[l] * (1.0f - Osp[j * O_ + l]) + (float)s;
    }
    float mx = m;
#pragma unroll
    for (int off = 16; off > 0; off >>= 1)
      mx = fmaxf(mx, __shfl_xor(mx, off, 32));
    float eo = (l < O_) ? expf(m - mx) : 0.f;
    float se = eo;
#pragma unroll
    for (int off = 16; off > 0; off >>= 1) se += __shfl_xor(se, off, 32);
    if (l < O_) {
      float sp = (m - 0.3f) > 0.f ? 1.f : 0.f;
      Om[j * O_ + l] = m;
      Osp[j * O_ + l] = sp;
      Osu[j * O_ + l] += sp;
      Mo[j * O_ + l] += eo / se;
    }
  }
#undef REDP
}

// ---------------------------------------------------------------------------
// Final o-phase (t=49) + output write. 256 blocks x 64 threads.
// ---------------------------------------------------------------------------
__global__ void final_k(const double* __restrict__ Po,
                        const float* __restrict__ AlphaO,
                        const float* __restrict__ Om,
                        const float* __restrict__ Osp,
                        const float* __restrict__ Osu,
                        const float* __restrict__ Mo, float* __restrict__ out) {
  __shared__ float om_l[O_];
  const int j = blockIdx.x, tid = threadIdx.x;
  if (tid < O_) {
    const double* pp = Po + ((size_t)(256 + j) * 64) * 20 + tid;   // slot 1
    double s = 0.0;
#pragma unroll
    for (int n2 = 0; n2 < 64; ++n2) s += pp[n2 * 20];
    float r = (float)s;
    float m = Om[j * O_ + tid] * AlphaO[tid] * (1.0f - Osp[j * O_ + tid]) + r;
    om_l[tid] = m;
  }
  __syncthreads();
  if (tid < O_) {
    float m = om_l[tid];
    float mx = om_l[0];
#pragma unroll
    for (int o = 1; o < O_; ++o) mx = fmaxf(mx, om_l[o]);
    float se = 0.f;
#pragma unroll
    for (int o = 0; o < O_; ++o) se += expf(om_l[o] - mx);
    float sp = (m - 0.3f) > 0.f ? 1.f : 0.f;
    out[j * O_ + tid] = (Osu[j * O_ + tid] + sp) / 50.0f;
    out[B_ * O_ + j * O_ + tid] = Mo[j * O_ + tid] + expf(m - mx) / se;
  }
}

// ---------------------------------------------------------------------------
extern "C" void kernel_launch(void* const* d_in, const int* in_sizes, int n_in,
                              void* d_out, int out_size, void* d_ws, size_t ws_size,
                              hipStream_t stream) {
  const float* input = (const float*)d_in[0];
  const float* w_ih  = (const float*)d_in[1];
  const float* w_hh  = (const float*)d_in[2];
  const float* w_ho  = (const float*)d_in[3];
  const float* tau_h = (const float*)d_in[4];
  const float* tau_o = (const float*)d_in[5];

  char* ws = (char*)d_ws;
  // layout (bytes):
  // Wtl    @ 0          18,874,368
  // Xin    @ 18874368   13,107,200
  // Xs     @ 31981568    1,048,576
  // Po     @ 33030144    5,242,880   (2 x 256 x 64 x 20 doubles)
  // Hm     @ 38273024    2,097,152   ([h 2048][b 256] floats)
  // WhoD   @ 40370176      327,680
  // AlphaH @ 40697856        8,192
  // AlphaO @ 40706048          128
  // Om     @ 40706176       20,480  (then Osp, Osu, Mo)
  int8_t* Wtl    = (int8_t*)(ws);
  int8_t* Xin    = (int8_t*)(ws + 18874368);
  int8_t* Xs     = (int8_t*)(ws + 31981568);
  double* Po     = (double*)(ws + 33030144);
  float*  Hm     = (float*)(ws + 38273024);
  double* WhoD   = (double*)(ws + 40370176);
  float*  AlphaH = (float*)(ws + 40697856);
  float*  AlphaO = (float*)(ws + 40706048);
  float*  Om     = (float*)(ws + 40706176);
  float*  Osp    = (float*)(ws + 40726656);
  float*  Osu    = (float*)(ws + 40747136);
  float*  Mo     = (float*)(ws + 40767616);
  float*  out    = (float*)d_out;

  prep_w<<<2048 * 9, 256, 0, stream>>>(w_ih, w_hh, Wtl);
  init_k<<<256, 256, 0, stream>>>(Xin, Xs, Hm, input, tau_h, tau_o, AlphaH,
                                  AlphaO, w_ho, WhoD, Om, Osp, Osu, Mo);
  for (int t = 0; t < T_; ++t) {
    step_k<<<256, 512, 0, stream>>>(Wtl, Xin, Xs, Hm, Po, WhoD, AlphaH, AlphaO,
                                    Om, Osp, Osu, Mo, t);
  }
  final_k<<<256, 64, 0, stream>>>(Po, AlphaO, Om, Osp, Osu, Mo, out);
}

// Round 7
// 890.685 us; speedup vs baseline: 3.6008x; 1.0911x over previous
//
#include <hip/hip_runtime.h>
#include <stdint.h>
#include <math.h>

// ---------------------------------------------------------------------------
// RSNN forward, MI355X. EXACT integer hidden GEMM (absmax 0.0156): 27-bit
// fixed-point weights -> 3 signed base-256 i8 digit planes, binary
// activations, i32 MFMA, exact int64 recombination, single fp32 round,
// fp32 program-order decay.
// Round-17: r11 skeleton (best measured: 900.8 us; K-eighth wave split,
// zero operand duplication: A 192 KB + B 288 KB per CU per step, 2-round
// LDS merge, 4 barriers) + two surgical fixes:
//  (1) Hm fragment-contiguous: thread's 4 membrane cells = one float4 at
//      Hm[(j*512+tid)*4] (w_e==k for both rounds) -> 1 coalesced 4 KB
//      load+store per epilogue wave (was 4 scattered scalar round-trips;
//      r16's [h][b] float4 was 64 lines/wave -- measured pessimization).
//  (2) Head o-phase coalesced: 40 lanes x 32-elem sums (~4 lines/load,
//      was 20), halves merged via one __shfl. Benign double-order change.
// ---------------------------------------------------------------------------

#define B_   256
#define T_   50
#define I_   1024
#define H_   2048
#define O_   20
#define XIN_T  262144    // input bytes per t: 4 bg * 16 kx * 4096
#define XS_BUF 524288    // one spike buffer: 4 bg * 32 kx * 4096
#define WNT 294912       // weight bytes per nt (32 cols): 3 * 48 * 2048
#define WPL 98304        // bytes per plane within an nt

typedef __attribute__((ext_vector_type(4))) int intx4;
typedef long long ll_t;

// ---------------------------------------------------------------------------
// Weight prep: digit p of W(n,kk) -> [nt 64][p 3][kx 48][row 32][64B]
// ---------------------------------------------------------------------------
__device__ __forceinline__ int digit_of(float v, int p) {
  int W = (int)rintf(v * 134217728.0f);   // exact: |W| <= 2^22
  int c0 = ((W + 128) & 255) - 128;
  int W1 = (W - c0) >> 8;
  int c1 = ((W1 + 128) & 255) - 128;
  int W2 = (W1 - c1) >> 8;
  return (p == 0) ? c0 : (p == 1) ? c1 : W2;
}

__global__ void prep_w(const float* __restrict__ w_ih,
                       const float* __restrict__ w_hh,
                       int8_t* __restrict__ Wtl) {
  int blk = blockIdx.x;
  int n = blk / 9, kg = blk % 9;
  int k9 = (kg * 256 + (int)threadIdx.x) * 4;   // [0, 9216)
  int p = k9 / 3072, kk = k9 % 3072;
  const float* src = (kk < 1024) ? (w_ih + n * I_ + kk)
                                 : (w_hh + n * H_ + (kk - 1024));
  float4 v = *(const float4*)src;
  int d0 = digit_of(v.x, p) & 255;
  int d1 = digit_of(v.y, p) & 255;
  int d2 = digit_of(v.z, p) & 255;
  int d3 = digit_of(v.w, p) & 255;
  int packed = d0 | (d1 << 8) | (d2 << 16) | (d3 << 24);
  size_t off = (size_t)(n >> 5) * WNT + (size_t)p * WPL + (kk >> 6) * 2048 +
               (n & 31) * 64 + (kk & 63);
  *(int*)(Wtl + off) = packed;
}

// ---------------------------------------------------------------------------
// Init: pack input for ALL t, zero spike buf0 + Hm + o-state, tables.
// ---------------------------------------------------------------------------
__global__ void init_k(int8_t* __restrict__ Xin, int8_t* __restrict__ Xs,
                       float* __restrict__ Hm, const float* __restrict__ input,
                       const float* __restrict__ tau_h,
                       const float* __restrict__ tau_o,
                       float* __restrict__ AlphaH, float* __restrict__ AlphaO,
                       const float* __restrict__ w_ho, double* __restrict__ WhoD,
                       float* __restrict__ Om, float* __restrict__ Osp,
                       float* __restrict__ Osu, float* __restrict__ Mo) {
  int id = blockIdx.x * 256 + threadIdx.x;   // [0, 65536)
  {
    int b = id >> 8, i4 = (id & 255) * 4;
    for (int t = 0; t < T_; ++t) {
      float4 v = *(const float4*)(input + ((size_t)(b * T_ + t) << 10) + i4);
      uchar4 pk;
      pk.x = v.x > 0.5f ? 1 : 0;
      pk.y = v.y > 0.5f ? 1 : 0;
      pk.z = v.z > 0.5f ? 1 : 0;
      pk.w = v.w > 0.5f ? 1 : 0;
      *(uchar4*)(Xin + (size_t)t * XIN_T + (b >> 6) * 65536 + (i4 >> 6) * 4096 +
                 (b & 63) * 64 + (i4 & 63)) = pk;
    }
  }
  *(double*)(Xs + (size_t)id * 8) = 0.0;        // zero spike buf0
  *(float4*)(Hm + (size_t)id * 8) = make_float4(0.f, 0.f, 0.f, 0.f);
  *(float4*)(Hm + (size_t)id * 8 + 4) = make_float4(0.f, 0.f, 0.f, 0.f);
  if (id < 64 * O_ * 32) {                      // WhoD [nt 64][o 20][hl 32]
    int nt = id / 640, rem = id % 640, o = rem / 32, hl = rem & 31;
    WhoD[id] = (double)w_ho[o * H_ + nt * 32 + hl];
  }
  if (id < H_) AlphaH[id] = (float)exp((double)(-1.0f / tau_h[id]));
  if (id < O_) AlphaO[id] = (float)exp((double)(-1.0f / tau_o[id]));
  if (id < B_ * O_) {
    Om[id] = 0.f; Osp[id] = 0.f; Osu[id] = 0.f; Mo[id] = 0.f;
  }
}

// ---------------------------------------------------------------------------
// Per-step kernel: 256 blocks x 512 threads (1/CU, 2 waves/SIMD).
// Block (nt in [0,64), mg in [0,4)): 64 batch x 32 h, full K.
// Wave k in [0,8) = K-eighth (6 slabs), 4fr x 2fc x 3p acc per wave.
// ---------------------------------------------------------------------------
__global__ __launch_bounds__(512, 2) void step_k(
    const int8_t* __restrict__ Wtl, const int8_t* __restrict__ Xin,
    int8_t* __restrict__ Xs, float* __restrict__ Hm, double* __restrict__ Po,
    const double* __restrict__ WhoD, const float* __restrict__ AlphaH,
    const float* __restrict__ AlphaO, float* __restrict__ Om,
    float* __restrict__ Osp, float* __restrict__ Osu, float* __restrict__ Mo,
    int t) {
  __shared__ double WhoL[640];
  __shared__ __align__(16) int8_t red[98304];   // [wave 8][frag 12][lane 64][16B]
  __shared__ int8_t spk_lT[2048];               // [h 32][b 64]

  const int j = blockIdx.x;                     // [0,256)
  const int nt = (j & 7) * 8 + ((j >> 3) & 7);  // same nt -> same j%8 (XCD)
  const int mg = j >> 6;                        // 64-batch group [0,4)
  const int tid = threadIdx.x;
  const int l = tid & 63, k = tid >> 6;
  const int r_ = l & 15, q = l >> 4;

  for (int i = tid; i < 640; i += 512) WhoL[i] = WhoD[nt * 640 + i];

  // fixed per-thread epilogue coordinates (wave role is static; w_e == k)
  const int fr_e = (k < 4) ? (k >> 1) : (2 + ((k - 4) >> 1));
  const int fc_e = k & 1;
  const int h_e = nt * 32 + fc_e * 16 + r_;

  // ---- K-loop: 6 slabs per wave, no barriers, depth-1 rotation ----
  const int arow = r_ * 64 + q * 16;
  const int8_t* Ain = Xin + (size_t)t * XIN_T + mg * 65536 + arow;
  const int8_t* Asp = Xs + (size_t)(t & 1) * XS_BUF + mg * 131072 + arow;
  int8_t* Xw = Xs + (size_t)((t + 1) & 1) * XS_BUF;
  const int8_t* Bw = Wtl + (size_t)nt * WNT + arow;
  const int u0 = k * 6;

  intx4 acc[4][2][3];   // [fr][fc][p]
#pragma unroll
  for (int fr = 0; fr < 4; ++fr)
#pragma unroll
    for (int fc = 0; fc < 2; ++fc)
#pragma unroll
      for (int p = 0; p < 3; ++p) acc[fr][fc][p] = (intx4){0, 0, 0, 0};

  intx4 a[2][4], b[2][2][3];
  {
    const int8_t* ap = (u0 < 16) ? (Ain + u0 * 4096) : (Asp + (u0 - 16) * 4096);
#pragma unroll
    for (int fr = 0; fr < 4; ++fr) a[0][fr] = *(const intx4*)(ap + fr * 1024);
    const int8_t* bp = Bw + u0 * 2048;
#pragma unroll
    for (int p = 0; p < 3; ++p)
#pragma unroll
      for (int fc = 0; fc < 2; ++fc)
        b[0][fc][p] = *(const intx4*)(bp + p * WPL + fc * 1024);
  }
#pragma unroll
  for (int i = 0; i < 6; ++i) {
    const int cur = i & 1, nxt = cur ^ 1;
    if (i < 5) {
      const int un = u0 + i + 1;
      const int8_t* ap = (un < 16) ? (Ain + un * 4096) : (Asp + (un - 16) * 4096);
#pragma unroll
      for (int fr = 0; fr < 4; ++fr) a[nxt][fr] = *(const intx4*)(ap + fr * 1024);
      const int8_t* bp = Bw + un * 2048;
#pragma unroll
      for (int p = 0; p < 3; ++p)
#pragma unroll
        for (int fc = 0; fc < 2; ++fc)
          b[nxt][fc][p] = *(const intx4*)(bp + p * WPL + fc * 1024);
    }
#pragma unroll
    for (int fr = 0; fr < 4; ++fr)
#pragma unroll
      for (int fc = 0; fc < 2; ++fc)
#pragma unroll
        for (int p = 0; p < 3; ++p)
          acc[fr][fc][p] = __builtin_amdgcn_mfma_i32_16x16x64_i8(
              a[cur][fr], b[cur][fc][p], acc[fr][fc][p], 0, 0, 0);
  }

  // ---- exact K-eighth merge: two all-to-all LDS rounds, parallel epilogue --
#define REDP(w, idx) (red + (((w) * 12 + (idx)) * 64 + l) * 16)

  // fragment-contiguous membrane: thread's 4 cells = float4 at (j*512+tid)
  float* hm_ptr = Hm + (size_t)(j * 512 + tid) * 4;

  auto epilogue = [&](intx4 s0, intx4 s1, intx4 s2) {
    const float alpha = AlphaH[h_e];
    float4 hp4 = *(float4*)hm_ptr;
    float* hp = reinterpret_cast<float*>(&hp4);
    unsigned spkpack = 0;
#pragma unroll
    for (int jj = 0; jj < 4; ++jj) {
      ll_t Sv = (ll_t)s0[jj] + ((ll_t)s1[jj] << 8) + ((ll_t)s2[jj] << 16);
      float M = (float)((double)Sv * 7.450580596923828125e-9);  // * 2^-27
      float hpv = hp[jj];
      float spf = (hpv - 0.3f) > 0.f ? 1.f : 0.f;
      float hmn = M + hpv * alpha * (1.0f - spf);   // fp32 program order
      hp[jj] = hmn;
      unsigned spk = (hmn - 0.3f) > 0.f ? 1u : 0u;
      const int brl = fr_e * 16 + q * 4 + jj;        // batch row [0,64)
      Xw[mg * 131072 + (h_e >> 6) * 4096 + brl * 64 + (h_e & 63)] =
          (int8_t)spk;
      spkpack |= spk << (8 * jj);
    }
    *(float4*)hm_ptr = hp4;
    *(unsigned*)(spk_lT + (fc_e * 16 + r_) * 64 + fr_e * 16 + q * 4) =
        spkpack;
  };

  // ---- Round A: fragments fr 0..1 -> waves 0..3 merge + epilogue ----
#pragma unroll
  for (int fr = 0; fr < 2; ++fr)
#pragma unroll
    for (int fc = 0; fc < 2; ++fc)
#pragma unroll
      for (int p = 0; p < 3; ++p)
        *(intx4*)REDP(k, (fr * 2 + fc) * 3 + p) = acc[fr][fc][p];
  __syncthreads();
  if (k < 4) {
    const int base = (fr_e * 2 + fc_e) * 3;
    intx4 s0 = (intx4){0, 0, 0, 0}, s1 = s0, s2 = s0;
#pragma unroll
    for (int w = 0; w < 8; ++w) {
      s0 = s0 + *(const intx4*)REDP(w, base + 0);
      s1 = s1 + *(const intx4*)REDP(w, base + 1);
      s2 = s2 + *(const intx4*)REDP(w, base + 2);
    }
    epilogue(s0, s1, s2);
  }
  __syncthreads();
  // ---- Round B: fragments fr 2..3 -> waves 4..7 merge + epilogue ----
#pragma unroll
  for (int fr = 0; fr < 2; ++fr)
#pragma unroll
    for (int fc = 0; fc < 2; ++fc)
#pragma unroll
      for (int p = 0; p < 3; ++p)
        *(intx4*)REDP(k, (fr * 2 + fc) * 3 + p) = acc[2 + fr][fc][p];
  __syncthreads();
  if (k >= 4) {
    const int base = ((fr_e - 2) * 2 + fc_e) * 3;
    intx4 s0 = (intx4){0, 0, 0, 0}, s1 = s0, s2 = s0;
#pragma unroll
    for (int w = 0; w < 8; ++w) {
      s0 = s0 + *(const intx4*)REDP(w, base + 0);
      s1 = s1 + *(const intx4*)REDP(w, base + 1);
      s2 = s2 + *(const intx4*)REDP(w, base + 2);
    }
    epilogue(s0, s1, s2);
  }
  __syncthreads();

  // ---- o-partials (waves 0-3) || head o-phase for t-1 (wave 7) ----
  if (tid < 256) {
    const int bl = tid >> 2, og = (tid & 3) * 5;
    const double* W0 = WhoL + og * 32;
    double a0 = 0, a1 = 0, a2 = 0, a3 = 0, a4 = 0;
#pragma unroll
    for (int hl = 0; hl < 32; ++hl) {
      double m = (double)spk_lT[hl * 64 + bl];
      a0 += m * W0[hl];
      a1 += m * W0[32 + hl];
      a2 += m * W0[64 + hl];
      a3 += m * W0[96 + hl];
      a4 += m * W0[128 + hl];
    }
    double* dst =
        Po + ((size_t)((t & 1) * 256 + mg * 64 + bl) * 64 + nt) * 20 + og;
    dst[0] = a0; dst[1] = a1; dst[2] = a2; dst[3] = a3; dst[4] = a4;
  } else if (k == 7 && t > 0) {
    // head: o-phase for step t-1, batch j. 40 lanes sum 32 nt each
    // (coalesced ~4 lines/load vs 20-lane stride-160B), halves merged
    // via one shuffle. Benign double-order change.
    const double* pb = Po + ((size_t)(((t - 1) & 1) * 256 + j) * 64) * 20;
    double s = 0.0;
    if (l < 40) {
      const int half = (l >= 20) ? 1 : 0;
      const int oo = l - half * 20;
      const double* pp = pb + (size_t)(half * 32) * 20 + oo;
#pragma unroll
      for (int n2 = 0; n2 < 32; ++n2) s += pp[n2 * 20];
    }
    double s_hi = __shfl(s, l + 20, 64);   // lanes 0..19 pull 20..39
    float m = -3.0e38f;
    if (l < O_)
      m = Om[j * O_ + l] * AlphaO[l] * (1.0f - Osp[j * O_ + l]) +
          (float)(s + s_hi);
    float mx = m;
#pragma unroll
    for (int off = 16; off > 0; off >>= 1)
      mx = fmaxf(mx, __shfl_xor(mx, off, 32));
    float eo = (l < O_) ? expf(m - mx) : 0.f;
    float se = eo;
#pragma unroll
    for (int off = 16; off > 0; off >>= 1) se += __shfl_xor(se, off, 32);
    if (l < O_) {
      float sp = (m - 0.3f) > 0.f ? 1.f : 0.f;
      Om[j * O_ + l] = m;
      Osp[j * O_ + l] = sp;
      Osu[j * O_ + l] += sp;
      Mo[j * O_ + l] += eo / se;
    }
  }
#undef REDP
}

// ---------------------------------------------------------------------------
// Final o-phase (t=49) + output write. 256 blocks x 64 threads.
// ---------------------------------------------------------------------------
__global__ void final_k(const double* __restrict__ Po,
                        const float* __restrict__ AlphaO,
                        const float* __restrict__ Om,
                        const float* __restrict__ Osp,
                        const float* __restrict__ Osu,
                        const float* __restrict__ Mo, float* __restrict__ out) {
  __shared__ float om_l[O_];
  const int j = blockIdx.x, tid = threadIdx.x;
  if (tid < O_) {
    const double* pp = Po + ((size_t)(256 + j) * 64) * 20 + tid;   // slot 1
    double s = 0.0;
#pragma unroll
    for (int n2 = 0; n2 < 64; ++n2) s += pp[n2 * 20];
    float r = (float)s;
    float m = Om[j * O_ + tid] * AlphaO[tid] * (1.0f - Osp[j * O_ + tid]) + r;
    om_l[tid] = m;
  }
  __syncthreads();
  if (tid < O_) {
    float m = om_l[tid];
    float mx = om_l[0];
#pragma unroll
    for (int o = 1; o < O_; ++o) mx = fmaxf(mx, om_l[o]);
    float se = 0.f;
#pragma unroll
    for (int o = 0; o < O_; ++o) se += expf(om_l[o] - mx);
    float sp = (m - 0.3f) > 0.f ? 1.f : 0.f;
    out[j * O_ + tid] = (Osu[j * O_ + tid] + sp) / 50.0f;
    out[B_ * O_ + j * O_ + tid] = Mo[j * O_ + tid] + expf(m - mx) / se;
  }
}

// ---------------------------------------------------------------------------
extern "C" void kernel_launch(void* const* d_in, const int* in_sizes, int n_in,
                              void* d_out, int out_size, void* d_ws, size_t ws_size,
                              hipStream_t stream) {
  const float* input = (const float*)d_in[0];
  const float* w_ih  = (const float*)d_in[1];
  const float* w_hh  = (const float*)d_in[2];
  const float* w_ho  = (const float*)d_in[3];
  const float* tau_h = (const float*)d_in[4];
  const float* tau_o = (const float*)d_in[5];

  char* ws = (char*)d_ws;
  // layout (bytes):
  // Wtl    @ 0          18,874,368
  // Xin    @ 18874368   13,107,200
  // Xs     @ 31981568    1,048,576
  // Po     @ 33030144    5,242,880   (2 x 256 x 64 x 20 doubles)
  // Hm     @ 38273024    2,097,152   (fragment-contiguous, [blk 256][tid 512][4])
  // WhoD   @ 40370176      327,680
  // AlphaH @ 40697856        8,192
  // AlphaO @ 40706048          128
  // Om     @ 40706176       20,480  (then Osp, Osu, Mo)
  int8_t* Wtl    = (int8_t*)(ws);
  int8_t* Xin    = (int8_t*)(ws + 18874368);
  int8_t* Xs     = (int8_t*)(ws + 31981568);
  double* Po     = (double*)(ws + 33030144);
  float*  Hm     = (float*)(ws + 38273024);
  double* WhoD   = (double*)(ws + 40370176);
  float*  AlphaH = (float*)(ws + 40697856);
  float*  AlphaO = (float*)(ws + 40706048);
  float*  Om     = (float*)(ws + 40706176);
  float*  Osp    = (float*)(ws + 40726656);
  float*  Osu    = (float*)(ws + 40747136);
  float*  Mo     = (float*)(ws + 40767616);
  float*  out    = (float*)d_out;

  prep_w<<<2048 * 9, 256, 0, stream>>>(w_ih, w_hh, Wtl);
  init_k<<<256, 256, 0, stream>>>(Xin, Xs, Hm, input, tau_h, tau_o, AlphaH,
                                  AlphaO, w_ho, WhoD, Om, Osp, Osu, Mo);
  for (int t = 0; t < T_; ++t) {
    step_k<<<256, 512, 0, stream>>>(Wtl, Xin, Xs, Hm, Po, WhoD, AlphaH, AlphaO,
                                    Om, Osp, Osu, Mo, t);
  }
  final_k<<<256, 64, 0, stream>>>(Po, AlphaO, Om, Osp, Osu, Mo, out);
}